// Round 8
// baseline (366.914 us; speedup 1.0000x reference)
//
#include <hip/hip_runtime.h>
#include <hip/hip_bf16.h>

#define B_   4
#define T_   2048
#define D_   1024
#define HQ_  16
#define HKV_ 4
#define HD_  64
#define NQKV_ 1536

typedef __attribute__((ext_vector_type(4))) float f32x4;
typedef _Float16 f16x8 __attribute__((ext_vector_type(8)));
typedef __attribute__((ext_vector_type(8))) unsigned short u16x8;

static __device__ __forceinline__ float h2f(unsigned short u) {
    union { unsigned short u; _Float16 h; } c; c.u = u; return (float)c.h;
}
static __device__ __forceinline__ unsigned short f2h(float f) {
    union { _Float16 h; unsigned short u; } c; c.h = (_Float16)f; return c.u;
}

#define GLL16(gsrc, ldst) \
    __builtin_amdgcn_global_load_lds((const __attribute__((address_space(1))) unsigned int*)(gsrc), \
                                     (__attribute__((address_space(3))) unsigned int*)(ldst), 16, 0, 0)

// ---------------------------------------------------------------- cast f32->f16
__global__ __launch_bounds__(256) void k_cast(const float* __restrict__ in,
                                              unsigned short* __restrict__ out, int n4) {
    int i = blockIdx.x * blockDim.x + threadIdx.x;
    int stride = gridDim.x * blockDim.x;
    for (; i < n4; i += stride) {
        f32x4 v = ((const f32x4*)in)[i];
        unsigned long long r;
        r  = (unsigned long long)f2h(v.x);
        r |= (unsigned long long)f2h(v.y) << 16;
        r |= (unsigned long long)f2h(v.z) << 32;
        r |= (unsigned long long)f2h(v.w) << 48;
        ((unsigned long long*)out)[i] = r;
    }
}

// ---------------------------------------------------------------- GEMM  C = A(MxK) * B(NxK)^T  (verified)
template <bool F16OUT>
__global__ __launch_bounds__(256) void k_gemm_bt(const unsigned short* __restrict__ A,
                                                 const unsigned short* __restrict__ Bw,
                                                 void* __restrict__ Cv, int M, int N, int K) {
    __shared__ __attribute__((aligned(16))) unsigned short As[128 * 32];
    __shared__ __attribute__((aligned(16))) unsigned short Bs[128 * 32];
    const int tid = threadIdx.x;
    const int w = tid >> 6, lane = tid & 63;
    const int gq = lane >> 4, n16 = lane & 15;
    const long gm0 = (long)blockIdx.y * 128, gn0 = (long)blockIdx.x * 128;
    const int wm = (w >> 1) * 64, wn = (w & 1) * 64;

    f32x4 acc[4][4] = {};

    const int KT = K >> 5;
    const int srow0 = w * 32 + (lane >> 2);
    unsigned short* alds = &As[w * 1024];
    unsigned short* blds = &Bs[w * 1024];

    auto stage = [&](int kt) {
        const int k0 = kt * 32;
#pragma unroll
        for (int i = 0; i < 2; i++) {
            int row = srow0 + i * 16;
            int chk = (lane & 3) ^ ((row >> 1) & 3);
            GLL16(A  + (gm0 + row) * K + k0 + chk * 8, alds + i * 512);
            GLL16(Bw + (gn0 + row) * K + k0 + chk * 8, blds + i * 512);
        }
    };

    stage(0);
    for (int kt = 0; kt < KT; ++kt) {
        __syncthreads();
        f16x8 af[4], bf[4];
#pragma unroll
        for (int mf = 0; mf < 4; mf++) {
            int row = wm + mf * 16 + n16;
            int chk = gq ^ ((row >> 1) & 3);
            af[mf] = *(const f16x8*)&As[row * 32 + chk * 8];
        }
#pragma unroll
        for (int nf = 0; nf < 4; nf++) {
            int row = wn + nf * 16 + n16;
            int chk = gq ^ ((row >> 1) & 3);
            bf[nf] = *(const f16x8*)&Bs[row * 32 + chk * 8];
        }
#pragma unroll
        for (int mf = 0; mf < 4; mf++)
#pragma unroll
            for (int nf = 0; nf < 4; nf++)
                acc[mf][nf] = __builtin_amdgcn_mfma_f32_16x16x32_f16(af[mf], bf[nf], acc[mf][nf], 0, 0, 0);
        __syncthreads();
        if (kt + 1 < KT) stage(kt + 1);
    }

#pragma unroll
    for (int mf = 0; mf < 4; mf++)
#pragma unroll
        for (int nf = 0; nf < 4; nf++)
#pragma unroll
            for (int q = 0; q < 4; q++) {
                long r = gm0 + wm + mf * 16 + gq * 4 + q;
                long c = gn0 + wn + nf * 16 + n16;
                if (F16OUT)
                    ((unsigned short*)Cv)[r * N + c] = f2h(acc[mf][nf][q]);
                else
                    ((float*)Cv)[r * N + c] = acc[mf][nf][q];
            }
}

// ---------------------------------------------------------------- RoPE + scatter + V transpose (verified)
__global__ __launch_bounds__(256) void k_rope(const unsigned short* __restrict__ qkv,
                                              const float* __restrict__ cosb,
                                              const float* __restrict__ sinb,
                                              unsigned short* __restrict__ qs,
                                              unsigned short* __restrict__ kb,
                                              unsigned short* __restrict__ vt) {
    const int blk = blockIdx.x;
    const int b = blk >> 5;
    const int t0 = (blk & 31) * 64;
    const int tid = threadIdx.x;
    const float ALPHA = 0.125f * 1.44269504088896340736f; // HD^-0.5 * log2(e), folded into q

    for (int it = 0; it < 128; ++it) {
        int idx = it * 256 + tid;
        int p = idx & 511, tl = idx >> 9;
        int h = p >> 5, dp = p & 31;
        int t = t0 + tl;
        unsigned int v = *(const unsigned int*)&qkv[(long)(b * T_ + t) * NQKV_ + h * 64 + dp * 2];
        float q0 = h2f((unsigned short)v), q1 = h2f((unsigned short)(v >> 16));
        int d0 = dp * 2;
        float2 cc = *(const float2*)&cosb[t * 64 + d0];
        float2 ss = *(const float2*)&sinb[t * 64 + d0];
        float o0 = (q0 * cc.x - q1 * ss.x) * ALPHA;
        float o1 = (q1 * cc.y + q0 * ss.y) * ALPHA;
        unsigned int ov = (unsigned int)f2h(o0) | ((unsigned int)f2h(o1) << 16);
        *(unsigned int*)&qs[((long)(b * HQ_ + h) * T_ + t) * 64 + d0] = ov;
    }
    for (int it = 0; it < 32; ++it) {
        int idx = it * 256 + tid;
        int dp = idx & 31, g = (idx >> 5) & 3, tl = idx >> 7;
        int t = t0 + tl;
        unsigned int v = *(const unsigned int*)&qkv[(long)(b * T_ + t) * NQKV_ + 1024 + g * 128 + dp * 2];
        float k0 = h2f((unsigned short)v), k1 = h2f((unsigned short)(v >> 16));
        int d0 = dp * 2;
        float2 cc = *(const float2*)&cosb[t * 64 + d0];
        float2 ss = *(const float2*)&sinb[t * 64 + d0];
        float o0 = k0 * cc.x - k1 * ss.x;
        float o1 = k1 * cc.y + k0 * ss.y;
        unsigned int ov = (unsigned int)f2h(o0) | ((unsigned int)f2h(o1) << 16);
        *(unsigned int*)&kb[((long)(b * HKV_ + g) * T_ + t) * 64 + d0] = ov;
    }
    // V transpose: [t][d] -> [d][t]
    for (int it = 0; it < 8; ++it) {
        int idx = it * 256 + tid;
        int d = idx & 63, tc = (idx >> 6) & 7, g = idx >> 9;
        u16x8 vv;
#pragma unroll
        for (int j = 0; j < 8; ++j) {
            int t = t0 + tc * 8 + j;
            vv[j] = qkv[(long)(b * T_ + t) * NQKV_ + 1024 + g * 128 + 64 + d];
        }
        *(u16x8*)&vt[((long)(b * HKV_ + g) * 64 + d) * T_ + t0 + tc * 8] = vv;
    }
}

// ---------------------------------------------------------------- flash attention — barrier-free
// kf AND vf fragments direct from global (both patterns HW-verified); no Ks LDS, no __syncthreads.
// Ps is per-wave; same-wave DS pipe is in-order (write->read ordering via lgkmcnt+sched_barrier).
// Softmax sum reduce DEFERRED to epilogue (rl = per-lane partial; corr is group-uniform).
__global__ __launch_bounds__(256) void k_attn(const unsigned short* __restrict__ qs,
                                              const unsigned short* __restrict__ kb,
                                              const unsigned short* __restrict__ vt,
                                              unsigned short* __restrict__ ao) {
    __shared__ __attribute__((aligned(16))) unsigned short Ps[4][32 * 72];
    const int tid = threadIdx.x;
    const int w = tid >> 6, lane = tid & 63;
    const int gq = lane >> 4, n16 = lane & 15;
    const int bh = blockIdx.y;
    const int b = bh >> 4, h = bh & 15, g = h >> 2;
    const int qt0 = blockIdx.x * 128 + w * 32;

    f16x8 qf[2][2];
#pragma unroll
    for (int mf = 0; mf < 2; mf++)
#pragma unroll
        for (int ks = 0; ks < 2; ks++) {
            long t = qt0 + mf * 16 + n16;
            qf[mf][ks] = *(const f16x8*)&qs[((long)(b * HQ_ + h) * T_ + t) * 64 + ks * 32 + gq * 8];
        }

    f32x4 acc[2][4] = {};
    float rm[2][4], rl[2][4];
#pragma unroll
    for (int mf = 0; mf < 2; mf++)
#pragma unroll
        for (int q = 0; q < 4; q++) { rm[mf][q] = -1e30f; rl[mf][q] = 0.f; }

    const unsigned short* Kg = kb + (long)(b * HKV_ + g) * T_ * 64;  // + key*64 + d
    const unsigned short* Vt = vt + (long)(b * HKV_ + g) * 64 * T_;  // + d*T_ + t
    unsigned short* Pw = Ps[w];

    for (int kt = 0; kt < 32; ++kt) {
        // ---- K fragments direct from global (≡ verified LDS round-trip content)
        f16x8 kf[4][2];
#pragma unroll
        for (int j = 0; j < 4; j++)
#pragma unroll
            for (int ks = 0; ks < 2; ks++)
                kf[j][ks] = *(const f16x8*)&Kg[(long)(kt * 64 + j * 16 + n16) * 64 + ks * 32 + gq * 8];
        // ---- S = Q K^T
        f32x4 s[2][4] = {};
#pragma unroll
        for (int mf = 0; mf < 2; mf++)
#pragma unroll
            for (int j = 0; j < 4; j++) {
                s[mf][j] = __builtin_amdgcn_mfma_f32_16x16x32_f16(qf[mf][0], kf[j][0], s[mf][j], 0, 0, 0);
                s[mf][j] = __builtin_amdgcn_mfma_f32_16x16x32_f16(qf[mf][1], kf[j][1], s[mf][j], 0, 0, 0);
            }
        // ---- V fragments direct from global (verified); latency hides under softmax
        f16x8 vf[4][2];
#pragma unroll
        for (int dn = 0; dn < 4; dn++)
#pragma unroll
            for (int ks = 0; ks < 2; ks++)
                vf[dn][ks] = *(const f16x8*)&Vt[(long)(dn * 16 + n16) * T_ + kt * 64 + (ks * 4 + gq) * 8];
        // ---- online softmax (max reduce exact; sum kept as per-lane partial)
#pragma unroll
        for (int mf = 0; mf < 2; mf++)
#pragma unroll
            for (int q = 0; q < 4; q++) {
                float mx = fmaxf(fmaxf(s[mf][0][q], s[mf][1][q]), fmaxf(s[mf][2][q], s[mf][3][q]));
#pragma unroll
                for (int off = 1; off < 16; off <<= 1) mx = fmaxf(mx, __shfl_xor(mx, off, 64));
                float mnew = fmaxf(rm[mf][q], mx);
                float corr = __builtin_amdgcn_exp2f(rm[mf][q] - mnew);
                float rs = 0.f;
#pragma unroll
                for (int j = 0; j < 4; j++) {
                    float p = __builtin_amdgcn_exp2f(s[mf][j][q] - mnew);
                    s[mf][j][q] = p;
                    rs += p;
                }
                rl[mf][q] = rl[mf][q] * corr + rs;   // per-lane partial (corr uniform in group)
                rm[mf][q] = mnew;
#pragma unroll
                for (int dn = 0; dn < 4; dn++) acc[mf][dn][q] *= corr;
            }
        // ---- P (C-layout) -> LDS (f16)
#pragma unroll
        for (int mf = 0; mf < 2; mf++)
#pragma unroll
            for (int j = 0; j < 4; j++)
#pragma unroll
                for (int q = 0; q < 4; q++) {
                    int row = mf * 16 + gq * 4 + q;
                    Pw[row * 72 + j * 16 + n16] = f2h(s[mf][j][q]);
                }
        asm volatile("s_waitcnt lgkmcnt(0)" ::: "memory");
        __builtin_amdgcn_sched_barrier(0);
        // ---- PV via MFMA
        f16x8 pf[2][2];
#pragma unroll
        for (int mf = 0; mf < 2; mf++)
#pragma unroll
            for (int ks = 0; ks < 2; ks++)
                pf[mf][ks] = *(const f16x8*)&Pw[(mf * 16 + n16) * 72 + ks * 32 + gq * 8];
#pragma unroll
        for (int mf = 0; mf < 2; mf++)
#pragma unroll
            for (int dn = 0; dn < 4; dn++) {
                acc[mf][dn] = __builtin_amdgcn_mfma_f32_16x16x32_f16(pf[mf][0], vf[dn][0], acc[mf][dn], 0, 0, 0);
                acc[mf][dn] = __builtin_amdgcn_mfma_f32_16x16x32_f16(pf[mf][1], vf[dn][1], acc[mf][dn], 0, 0, 0);
            }
    }
    // ---- epilogue: finish the deferred sum reduce, then write O/l
#pragma unroll
    for (int mf = 0; mf < 2; mf++)
#pragma unroll
        for (int q = 0; q < 4; q++) {
            float rs = rl[mf][q];
#pragma unroll
            for (int off = 1; off < 16; off <<= 1) rs += __shfl_xor(rs, off, 64);
            float inv = 1.0f / rs;
            long t = qt0 + mf * 16 + gq * 4 + q;
#pragma unroll
            for (int dn = 0; dn < 4; dn++)
                ao[(long)(b * T_ + t) * D_ + h * 64 + dn * 16 + n16] = f2h(acc[mf][dn][q] * inv);
        }
}

// ---------------------------------------------------------------- launch
extern "C" void kernel_launch(void* const* d_in, const int* in_sizes, int n_in,
                              void* d_out, int out_size, void* d_ws, size_t ws_size,
                              hipStream_t stream) {
    const float* x    = (const float*)d_in[0];
    const float* cosb = (const float*)d_in[1];
    const float* sinb = (const float*)d_in[2];
    const float* Wq   = (const float*)d_in[3];
    const float* Wkv  = (const float*)d_in[4];
    const float* Wo   = (const float*)d_in[5];
    float* out = (float*)d_out;

    char* ws = (char*)d_ws;
    unsigned short* xb   = (unsigned short*)(ws);              // reused as attnout
    unsigned short* wcat = (unsigned short*)(ws + 16777216);   // [Wq ; Wkv]
    unsigned short* wob  = (unsigned short*)(ws + 19922944);
    unsigned short* qkvb = (unsigned short*)(ws + 22020096);
    unsigned short* qsb  = (unsigned short*)(ws + 47185920);
    unsigned short* vtb  = (unsigned short*)(ws + 63963136);
    unsigned short* kbuf = (unsigned short*)(ws + 68157440);

    k_cast<<<2048, 256, 0, stream>>>(x,   xb,             (B_ * T_ * D_) / 4);
    k_cast<<<1024, 256, 0, stream>>>(Wq,  wcat,           (D_ * D_) / 4);
    k_cast<<<512,  256, 0, stream>>>(Wkv, wcat + D_ * D_, (512 * D_) / 4);
    k_cast<<<1024, 256, 0, stream>>>(Wo,  wob,            (D_ * D_) / 4);

    k_gemm_bt<true><<<dim3(NQKV_ / 128, (B_ * T_) / 128), 256, 0, stream>>>(xb, wcat, qkvb, B_ * T_, NQKV_, D_);
    k_rope<<<B_ * (T_ / 64), 256, 0, stream>>>(qkvb, cosb, sinb, qsb, kbuf, vtb);
    k_attn<<<dim3(T_ / 128, B_ * HQ_), 256, 0, stream>>>(qsb, kbuf, vtb, xb);
    k_gemm_bt<false><<<dim3(D_ / 128, (B_ * T_) / 128), 256, 0, stream>>>(xb, wob, out, B_ * T_, D_, D_);
}

// Round 9
// 365.649 us; speedup vs baseline: 1.0035x; 1.0035x over previous
//
#include <hip/hip_runtime.h>
#include <hip/hip_bf16.h>

#define B_   4
#define T_   2048
#define D_   1024
#define HQ_  16
#define HKV_ 4
#define HD_  64
#define NQKV_ 1536

typedef __attribute__((ext_vector_type(4))) float f32x4;
typedef _Float16 f16x8 __attribute__((ext_vector_type(8)));
typedef __attribute__((ext_vector_type(8))) unsigned short u16x8;

static __device__ __forceinline__ float h2f(unsigned short u) {
    union { unsigned short u; _Float16 h; } c; c.u = u; return (float)c.h;
}
static __device__ __forceinline__ unsigned short f2h(float f) {
    union { _Float16 h; unsigned short u; } c; c.h = (_Float16)f; return c.u;
}

#define GLL16(gsrc, ldst) \
    __builtin_amdgcn_global_load_lds((const __attribute__((address_space(1))) unsigned int*)(gsrc), \
                                     (__attribute__((address_space(3))) unsigned int*)(ldst), 16, 0, 0)

// ---------------------------------------------------------------- cast f32->f16
__global__ __launch_bounds__(256) void k_cast(const float* __restrict__ in,
                                              unsigned short* __restrict__ out, int n4) {
    int i = blockIdx.x * blockDim.x + threadIdx.x;
    int stride = gridDim.x * blockDim.x;
    for (; i < n4; i += stride) {
        f32x4 v = ((const f32x4*)in)[i];
        unsigned long long r;
        r  = (unsigned long long)f2h(v.x);
        r |= (unsigned long long)f2h(v.y) << 16;
        r |= (unsigned long long)f2h(v.z) << 32;
        r |= (unsigned long long)f2h(v.w) << 48;
        ((unsigned long long*)out)[i] = r;
    }
}

// ---------------------------------------------------------------- GEMM  C = A(MxK) * B(NxK)^T  (verified)
template <bool F16OUT>
__global__ __launch_bounds__(256) void k_gemm_bt(const unsigned short* __restrict__ A,
                                                 const unsigned short* __restrict__ Bw,
                                                 void* __restrict__ Cv, int M, int N, int K) {
    __shared__ __attribute__((aligned(16))) unsigned short As[128 * 32];
    __shared__ __attribute__((aligned(16))) unsigned short Bs[128 * 32];
    const int tid = threadIdx.x;
    const int w = tid >> 6, lane = tid & 63;
    const int gq = lane >> 4, n16 = lane & 15;
    const long gm0 = (long)blockIdx.y * 128, gn0 = (long)blockIdx.x * 128;
    const int wm = (w >> 1) * 64, wn = (w & 1) * 64;

    f32x4 acc[4][4] = {};

    const int KT = K >> 5;
    const int srow0 = w * 32 + (lane >> 2);
    unsigned short* alds = &As[w * 1024];
    unsigned short* blds = &Bs[w * 1024];

    auto stage = [&](int kt) {
        const int k0 = kt * 32;
#pragma unroll
        for (int i = 0; i < 2; i++) {
            int row = srow0 + i * 16;
            int chk = (lane & 3) ^ ((row >> 1) & 3);
            GLL16(A  + (gm0 + row) * K + k0 + chk * 8, alds + i * 512);
            GLL16(Bw + (gn0 + row) * K + k0 + chk * 8, blds + i * 512);
        }
    };

    stage(0);
    for (int kt = 0; kt < KT; ++kt) {
        __syncthreads();
        f16x8 af[4], bf[4];
#pragma unroll
        for (int mf = 0; mf < 4; mf++) {
            int row = wm + mf * 16 + n16;
            int chk = gq ^ ((row >> 1) & 3);
            af[mf] = *(const f16x8*)&As[row * 32 + chk * 8];
        }
#pragma unroll
        for (int nf = 0; nf < 4; nf++) {
            int row = wn + nf * 16 + n16;
            int chk = gq ^ ((row >> 1) & 3);
            bf[nf] = *(const f16x8*)&Bs[row * 32 + chk * 8];
        }
#pragma unroll
        for (int mf = 0; mf < 4; mf++)
#pragma unroll
            for (int nf = 0; nf < 4; nf++)
                acc[mf][nf] = __builtin_amdgcn_mfma_f32_16x16x32_f16(af[mf], bf[nf], acc[mf][nf], 0, 0, 0);
        __syncthreads();
        if (kt + 1 < KT) stage(kt + 1);
    }

#pragma unroll
    for (int mf = 0; mf < 4; mf++)
#pragma unroll
        for (int nf = 0; nf < 4; nf++)
#pragma unroll
            for (int q = 0; q < 4; q++) {
                long r = gm0 + wm + mf * 16 + gq * 4 + q;
                long c = gn0 + wn + nf * 16 + n16;
                if (F16OUT)
                    ((unsigned short*)Cv)[r * N + c] = f2h(acc[mf][nf][q]);
                else
                    ((float*)Cv)[r * N + c] = acc[mf][nf][q];
            }
}

// ---------------------------------------------------------------- RoPE + scatter + V transpose (verified)
__global__ __launch_bounds__(256) void k_rope(const unsigned short* __restrict__ qkv,
                                              const float* __restrict__ cosb,
                                              const float* __restrict__ sinb,
                                              unsigned short* __restrict__ qs,
                                              unsigned short* __restrict__ kb,
                                              unsigned short* __restrict__ vt) {
    const int blk = blockIdx.x;
    const int b = blk >> 5;
    const int t0 = (blk & 31) * 64;
    const int tid = threadIdx.x;
    const float ALPHA = 0.125f * 1.44269504088896340736f; // HD^-0.5 * log2(e), folded into q

    for (int it = 0; it < 128; ++it) {
        int idx = it * 256 + tid;
        int p = idx & 511, tl = idx >> 9;
        int h = p >> 5, dp = p & 31;
        int t = t0 + tl;
        unsigned int v = *(const unsigned int*)&qkv[(long)(b * T_ + t) * NQKV_ + h * 64 + dp * 2];
        float q0 = h2f((unsigned short)v), q1 = h2f((unsigned short)(v >> 16));
        int d0 = dp * 2;
        float2 cc = *(const float2*)&cosb[t * 64 + d0];
        float2 ss = *(const float2*)&sinb[t * 64 + d0];
        float o0 = (q0 * cc.x - q1 * ss.x) * ALPHA;
        float o1 = (q1 * cc.y + q0 * ss.y) * ALPHA;
        unsigned int ov = (unsigned int)f2h(o0) | ((unsigned int)f2h(o1) << 16);
        *(unsigned int*)&qs[((long)(b * HQ_ + h) * T_ + t) * 64 + d0] = ov;
    }
    for (int it = 0; it < 32; ++it) {
        int idx = it * 256 + tid;
        int dp = idx & 31, g = (idx >> 5) & 3, tl = idx >> 7;
        int t = t0 + tl;
        unsigned int v = *(const unsigned int*)&qkv[(long)(b * T_ + t) * NQKV_ + 1024 + g * 128 + dp * 2];
        float k0 = h2f((unsigned short)v), k1 = h2f((unsigned short)(v >> 16));
        int d0 = dp * 2;
        float2 cc = *(const float2*)&cosb[t * 64 + d0];
        float2 ss = *(const float2*)&sinb[t * 64 + d0];
        float o0 = k0 * cc.x - k1 * ss.x;
        float o1 = k1 * cc.y + k0 * ss.y;
        unsigned int ov = (unsigned int)f2h(o0) | ((unsigned int)f2h(o1) << 16);
        *(unsigned int*)&kb[((long)(b * HKV_ + g) * T_ + t) * 64 + d0] = ov;
    }
    // V transpose: [t][d] -> [d][t]
    for (int it = 0; it < 8; ++it) {
        int idx = it * 256 + tid;
        int d = idx & 63, tc = (idx >> 6) & 7, g = idx >> 9;
        u16x8 vv;
#pragma unroll
        for (int j = 0; j < 8; ++j) {
            int t = t0 + tc * 8 + j;
            vv[j] = qkv[(long)(b * T_ + t) * NQKV_ + 1024 + g * 128 + 64 + d];
        }
        *(u16x8*)&vt[((long)(b * HKV_ + g) * 64 + d) * T_ + t0 + tc * 8] = vv;
    }
}

// ---------------------------------------------------------------- flash attention — barrier-free + K software pipeline
// kf loop-carried: loaded for kt+1 right after QK^T consumes it, so softmax+P+PV (~800cy) hides the L2 latency.
__global__ __launch_bounds__(256) void k_attn(const unsigned short* __restrict__ qs,
                                              const unsigned short* __restrict__ kb,
                                              const unsigned short* __restrict__ vt,
                                              unsigned short* __restrict__ ao) {
    __shared__ __attribute__((aligned(16))) unsigned short Ps[4][32 * 72];
    const int tid = threadIdx.x;
    const int w = tid >> 6, lane = tid & 63;
    const int gq = lane >> 4, n16 = lane & 15;
    const int bh = blockIdx.y;
    const int b = bh >> 4, h = bh & 15, g = h >> 2;
    const int qt0 = blockIdx.x * 128 + w * 32;

    f16x8 qf[2][2];
#pragma unroll
    for (int mf = 0; mf < 2; mf++)
#pragma unroll
        for (int ks = 0; ks < 2; ks++) {
            long t = qt0 + mf * 16 + n16;
            qf[mf][ks] = *(const f16x8*)&qs[((long)(b * HQ_ + h) * T_ + t) * 64 + ks * 32 + gq * 8];
        }

    f32x4 acc[2][4] = {};
    float rm[2][4], rl[2][4];
#pragma unroll
    for (int mf = 0; mf < 2; mf++)
#pragma unroll
        for (int q = 0; q < 4; q++) { rm[mf][q] = -1e30f; rl[mf][q] = 0.f; }

    const unsigned short* Kg = kb + (long)(b * HKV_ + g) * T_ * 64;  // + key*64 + d
    const unsigned short* Vt = vt + (long)(b * HKV_ + g) * 64 * T_;  // + d*T_ + t
    unsigned short* Pw = Ps[w];

    // peel: K fragments for tile 0
    f16x8 kf[4][2];
#pragma unroll
    for (int j = 0; j < 4; j++)
#pragma unroll
        for (int ks = 0; ks < 2; ks++)
            kf[j][ks] = *(const f16x8*)&Kg[(long)(j * 16 + n16) * 64 + ks * 32 + gq * 8];

    for (int kt = 0; kt < 32; ++kt) {
        // ---- S = Q K^T (consumes kf)
        f32x4 s[2][4] = {};
#pragma unroll
        for (int mf = 0; mf < 2; mf++)
#pragma unroll
            for (int j = 0; j < 4; j++) {
                s[mf][j] = __builtin_amdgcn_mfma_f32_16x16x32_f16(qf[mf][0], kf[j][0], s[mf][j], 0, 0, 0);
                s[mf][j] = __builtin_amdgcn_mfma_f32_16x16x32_f16(qf[mf][1], kf[j][1], s[mf][j], 0, 0, 0);
            }
        // ---- V fragments for THIS tile (cover: softmax+P)
        f16x8 vf[4][2];
#pragma unroll
        for (int dn = 0; dn < 4; dn++)
#pragma unroll
            for (int ks = 0; ks < 2; ks++)
                vf[dn][ks] = *(const f16x8*)&Vt[(long)(dn * 16 + n16) * T_ + kt * 64 + (ks * 4 + gq) * 8];
        // ---- K fragments for NEXT tile (loop-carried; cover: softmax+P+PV+backedge)
        {
            int ktn = (kt < 31) ? kt + 1 : kt;
#pragma unroll
            for (int j = 0; j < 4; j++)
#pragma unroll
                for (int ks = 0; ks < 2; ks++)
                    kf[j][ks] = *(const f16x8*)&Kg[(long)(ktn * 64 + j * 16 + n16) * 64 + ks * 32 + gq * 8];
        }
        // ---- online softmax (max reduce exact; sum kept as per-lane partial)
#pragma unroll
        for (int mf = 0; mf < 2; mf++)
#pragma unroll
            for (int q = 0; q < 4; q++) {
                float mx = fmaxf(fmaxf(s[mf][0][q], s[mf][1][q]), fmaxf(s[mf][2][q], s[mf][3][q]));
#pragma unroll
                for (int off = 1; off < 16; off <<= 1) mx = fmaxf(mx, __shfl_xor(mx, off, 64));
                float mnew = fmaxf(rm[mf][q], mx);
                float corr = __builtin_amdgcn_exp2f(rm[mf][q] - mnew);
                float rs = 0.f;
#pragma unroll
                for (int j = 0; j < 4; j++) {
                    float p = __builtin_amdgcn_exp2f(s[mf][j][q] - mnew);
                    s[mf][j][q] = p;
                    rs += p;
                }
                rl[mf][q] = rl[mf][q] * corr + rs;   // per-lane partial (corr uniform in group)
                rm[mf][q] = mnew;
#pragma unroll
                for (int dn = 0; dn < 4; dn++) acc[mf][dn][q] *= corr;
            }
        // ---- P (C-layout) -> LDS (f16)
#pragma unroll
        for (int mf = 0; mf < 2; mf++)
#pragma unroll
            for (int j = 0; j < 4; j++)
#pragma unroll
                for (int q = 0; q < 4; q++) {
                    int row = mf * 16 + gq * 4 + q;
                    Pw[row * 72 + j * 16 + n16] = f2h(s[mf][j][q]);
                }
        asm volatile("s_waitcnt lgkmcnt(0)" ::: "memory");
        __builtin_amdgcn_sched_barrier(0);
        // ---- PV via MFMA
        f16x8 pf[2][2];
#pragma unroll
        for (int mf = 0; mf < 2; mf++)
#pragma unroll
            for (int ks = 0; ks < 2; ks++)
                pf[mf][ks] = *(const f16x8*)&Pw[(mf * 16 + n16) * 72 + ks * 32 + gq * 8];
#pragma unroll
        for (int mf = 0; mf < 2; mf++)
#pragma unroll
            for (int dn = 0; dn < 4; dn++) {
                acc[mf][dn] = __builtin_amdgcn_mfma_f32_16x16x32_f16(pf[mf][0], vf[dn][0], acc[mf][dn], 0, 0, 0);
                acc[mf][dn] = __builtin_amdgcn_mfma_f32_16x16x32_f16(pf[mf][1], vf[dn][1], acc[mf][dn], 0, 0, 0);
            }
    }
    // ---- epilogue: finish the deferred sum reduce, then write O/l
#pragma unroll
    for (int mf = 0; mf < 2; mf++)
#pragma unroll
        for (int q = 0; q < 4; q++) {
            float rs = rl[mf][q];
#pragma unroll
            for (int off = 1; off < 16; off <<= 1) rs += __shfl_xor(rs, off, 64);
            float inv = 1.0f / rs;
            long t = qt0 + mf * 16 + gq * 4 + q;
#pragma unroll
            for (int dn = 0; dn < 4; dn++)
                ao[(long)(b * T_ + t) * D_ + h * 64 + dn * 16 + n16] = f2h(acc[mf][dn][q] * inv);
        }
}

// ---------------------------------------------------------------- launch
extern "C" void kernel_launch(void* const* d_in, const int* in_sizes, int n_in,
                              void* d_out, int out_size, void* d_ws, size_t ws_size,
                              hipStream_t stream) {
    const float* x    = (const float*)d_in[0];
    const float* cosb = (const float*)d_in[1];
    const float* sinb = (const float*)d_in[2];
    const float* Wq   = (const float*)d_in[3];
    const float* Wkv  = (const float*)d_in[4];
    const float* Wo   = (const float*)d_in[5];
    float* out = (float*)d_out;

    char* ws = (char*)d_ws;
    unsigned short* xb   = (unsigned short*)(ws);              // reused as attnout
    unsigned short* wcat = (unsigned short*)(ws + 16777216);   // [Wq ; Wkv]
    unsigned short* wob  = (unsigned short*)(ws + 19922944);
    unsigned short* qkvb = (unsigned short*)(ws + 22020096);
    unsigned short* qsb  = (unsigned short*)(ws + 47185920);
    unsigned short* vtb  = (unsigned short*)(ws + 63963136);
    unsigned short* kbuf = (unsigned short*)(ws + 68157440);

    k_cast<<<2048, 256, 0, stream>>>(x,   xb,             (B_ * T_ * D_) / 4);
    k_cast<<<1024, 256, 0, stream>>>(Wq,  wcat,           (D_ * D_) / 4);
    k_cast<<<512,  256, 0, stream>>>(Wkv, wcat + D_ * D_, (512 * D_) / 4);
    k_cast<<<1024, 256, 0, stream>>>(Wo,  wob,            (D_ * D_) / 4);

    k_gemm_bt<true><<<dim3(NQKV_ / 128, (B_ * T_) / 128), 256, 0, stream>>>(xb, wcat, qkvb, B_ * T_, NQKV_, D_);
    k_rope<<<B_ * (T_ / 64), 256, 0, stream>>>(qkvb, cosb, sinb, qsb, kbuf, vtb);
    k_attn<<<dim3(T_ / 128, B_ * HQ_), 256, 0, stream>>>(qsb, kbuf, vtb, xb);
    k_gemm_bt<false><<<dim3(D_ / 128, (B_ * T_) / 128), 256, 0, stream>>>(xb, wob, out, B_ * T_, D_, D_);
}

// Round 10
// 361.692 us; speedup vs baseline: 1.0144x; 1.0109x over previous
//
#include <hip/hip_runtime.h>
#include <hip/hip_bf16.h>

#define B_   4
#define T_   2048
#define D_   1024
#define HQ_  16
#define HKV_ 4
#define HD_  64
#define NQKV_ 1536

typedef __attribute__((ext_vector_type(4))) float f32x4;
typedef __attribute__((ext_vector_type(16))) float f32x16;
typedef _Float16 f16x8 __attribute__((ext_vector_type(8)));
typedef _Float16 f16x2 __attribute__((ext_vector_type(2)));
typedef __attribute__((ext_vector_type(8))) unsigned short u16x8;

static __device__ __forceinline__ float h2f(unsigned short u) {
    union { unsigned short u; _Float16 h; } c; c.u = u; return (float)c.h;
}
static __device__ __forceinline__ unsigned short f2h(float f) {
    union { _Float16 h; unsigned short u; } c; c.h = (_Float16)f; return c.u;
}

#define GLL16(gsrc, ldst) \
    __builtin_amdgcn_global_load_lds((const __attribute__((address_space(1))) unsigned int*)(gsrc), \
                                     (__attribute__((address_space(3))) unsigned int*)(ldst), 16, 0, 0)

// ---------------------------------------------------------------- cast f32->f16
__global__ __launch_bounds__(256) void k_cast(const float* __restrict__ in,
                                              unsigned short* __restrict__ out, int n4) {
    int i = blockIdx.x * blockDim.x + threadIdx.x;
    int stride = gridDim.x * blockDim.x;
    for (; i < n4; i += stride) {
        f32x4 v = ((const f32x4*)in)[i];
        unsigned long long r;
        r  = (unsigned long long)f2h(v.x);
        r |= (unsigned long long)f2h(v.y) << 16;
        r |= (unsigned long long)f2h(v.z) << 32;
        r |= (unsigned long long)f2h(v.w) << 48;
        ((unsigned long long*)out)[i] = r;
    }
}

// ---------------------------------------------------------------- GEMM  C = A(MxK) * B(NxK)^T  (verified)
template <bool F16OUT>
__global__ __launch_bounds__(256) void k_gemm_bt(const unsigned short* __restrict__ A,
                                                 const unsigned short* __restrict__ Bw,
                                                 void* __restrict__ Cv, int M, int N, int K) {
    __shared__ __attribute__((aligned(16))) unsigned short As[128 * 32];
    __shared__ __attribute__((aligned(16))) unsigned short Bs[128 * 32];
    const int tid = threadIdx.x;
    const int w = tid >> 6, lane = tid & 63;
    const int gq = lane >> 4, n16 = lane & 15;
    const long gm0 = (long)blockIdx.y * 128, gn0 = (long)blockIdx.x * 128;
    const int wm = (w >> 1) * 64, wn = (w & 1) * 64;

    f32x4 acc[4][4] = {};

    const int KT = K >> 5;
    const int srow0 = w * 32 + (lane >> 2);
    unsigned short* alds = &As[w * 1024];
    unsigned short* blds = &Bs[w * 1024];

    auto stage = [&](int kt) {
        const int k0 = kt * 32;
#pragma unroll
        for (int i = 0; i < 2; i++) {
            int row = srow0 + i * 16;
            int chk = (lane & 3) ^ ((row >> 1) & 3);
            GLL16(A  + (gm0 + row) * K + k0 + chk * 8, alds + i * 512);
            GLL16(Bw + (gn0 + row) * K + k0 + chk * 8, blds + i * 512);
        }
    };

    stage(0);
    for (int kt = 0; kt < KT; ++kt) {
        __syncthreads();
        f16x8 af[4], bf[4];
#pragma unroll
        for (int mf = 0; mf < 4; mf++) {
            int row = wm + mf * 16 + n16;
            int chk = gq ^ ((row >> 1) & 3);
            af[mf] = *(const f16x8*)&As[row * 32 + chk * 8];
        }
#pragma unroll
        for (int nf = 0; nf < 4; nf++) {
            int row = wn + nf * 16 + n16;
            int chk = gq ^ ((row >> 1) & 3);
            bf[nf] = *(const f16x8*)&Bs[row * 32 + chk * 8];
        }
#pragma unroll
        for (int mf = 0; mf < 4; mf++)
#pragma unroll
            for (int nf = 0; nf < 4; nf++)
                acc[mf][nf] = __builtin_amdgcn_mfma_f32_16x16x32_f16(af[mf], bf[nf], acc[mf][nf], 0, 0, 0);
        __syncthreads();
        if (kt + 1 < KT) stage(kt + 1);
    }

#pragma unroll
    for (int mf = 0; mf < 4; mf++)
#pragma unroll
        for (int nf = 0; nf < 4; nf++)
#pragma unroll
            for (int q = 0; q < 4; q++) {
                long r = gm0 + wm + mf * 16 + gq * 4 + q;
                long c = gn0 + wn + nf * 16 + n16;
                if (F16OUT)
                    ((unsigned short*)Cv)[r * N + c] = f2h(acc[mf][nf][q]);
                else
                    ((float*)Cv)[r * N + c] = acc[mf][nf][q];
            }
}

// ---------------------------------------------------------------- RoPE + scatter + V transpose (verified)
__global__ __launch_bounds__(256) void k_rope(const unsigned short* __restrict__ qkv,
                                              const float* __restrict__ cosb,
                                              const float* __restrict__ sinb,
                                              unsigned short* __restrict__ qs,
                                              unsigned short* __restrict__ kb,
                                              unsigned short* __restrict__ vt) {
    const int blk = blockIdx.x;
    const int b = blk >> 5;
    const int t0 = (blk & 31) * 64;
    const int tid = threadIdx.x;
    const float ALPHA = 0.125f * 1.44269504088896340736f; // HD^-0.5 * log2(e), folded into q

    for (int it = 0; it < 128; ++it) {
        int idx = it * 256 + tid;
        int p = idx & 511, tl = idx >> 9;
        int h = p >> 5, dp = p & 31;
        int t = t0 + tl;
        unsigned int v = *(const unsigned int*)&qkv[(long)(b * T_ + t) * NQKV_ + h * 64 + dp * 2];
        float q0 = h2f((unsigned short)v), q1 = h2f((unsigned short)(v >> 16));
        int d0 = dp * 2;
        float2 cc = *(const float2*)&cosb[t * 64 + d0];
        float2 ss = *(const float2*)&sinb[t * 64 + d0];
        float o0 = (q0 * cc.x - q1 * ss.x) * ALPHA;
        float o1 = (q1 * cc.y + q0 * ss.y) * ALPHA;
        unsigned int ov = (unsigned int)f2h(o0) | ((unsigned int)f2h(o1) << 16);
        *(unsigned int*)&qs[((long)(b * HQ_ + h) * T_ + t) * 64 + d0] = ov;
    }
    for (int it = 0; it < 32; ++it) {
        int idx = it * 256 + tid;
        int dp = idx & 31, g = (idx >> 5) & 3, tl = idx >> 7;
        int t = t0 + tl;
        unsigned int v = *(const unsigned int*)&qkv[(long)(b * T_ + t) * NQKV_ + 1024 + g * 128 + dp * 2];
        float k0 = h2f((unsigned short)v), k1 = h2f((unsigned short)(v >> 16));
        int d0 = dp * 2;
        float2 cc = *(const float2*)&cosb[t * 64 + d0];
        float2 ss = *(const float2*)&sinb[t * 64 + d0];
        float o0 = k0 * cc.x - k1 * ss.x;
        float o1 = k1 * cc.y + k0 * ss.y;
        unsigned int ov = (unsigned int)f2h(o0) | ((unsigned int)f2h(o1) << 16);
        *(unsigned int*)&kb[((long)(b * HKV_ + g) * T_ + t) * 64 + d0] = ov;
    }
    // V transpose: [t][d] -> [d][t]
    for (int it = 0; it < 8; ++it) {
        int idx = it * 256 + tid;
        int d = idx & 63, tc = (idx >> 6) & 7, g = idx >> 9;
        u16x8 vv;
#pragma unroll
        for (int j = 0; j < 8; ++j) {
            int t = t0 + tc * 8 + j;
            vv[j] = qkv[(long)(b * T_ + t) * NQKV_ + 1024 + g * 128 + 64 + d];
        }
        *(u16x8*)&vt[((long)(b * HKV_ + g) * 64 + d) * T_ + t0 + tc * 8] = vv;
    }
}

// ---------------------------------------------------------------- flash attention — swapped 32x32, in-register P
// Wave = 32 queries (la = lane&31). S^T = mfma32(K,Q): lane owns query la, keys lane-local.
// Softmax: scalar rm/rl per lane, 1 shuffle for cross-half max. P -> PV fully in-register
// (cvt_pkrtz + 4 predicated shfl_xor(32)/ktile + cndmask). PV: O^T = mfma32(V^T, P), V^T from vtb.
// NO LDS, NO barriers.
__global__ __launch_bounds__(256) void k_attn(const unsigned short* __restrict__ qs,
                                              const unsigned short* __restrict__ kb,
                                              const unsigned short* __restrict__ vt,
                                              unsigned short* __restrict__ ao) {
    const int tid = threadIdx.x;
    const int w = tid >> 6, lane = tid & 63;
    const int la = lane & 31;
    const bool hi = (lane >> 5) != 0;
    const int bh = blockIdx.y;
    const int b = bh >> 4, h = bh & 15, g = h >> 2;
    const int qt0 = blockIdx.x * 128 + w * 32;

    // Q B-fragments: col=query=la, k(d) = kd*16 + hi*8 + i
    const unsigned short* Qg = qs + ((long)(b * HQ_ + h) * T_ + qt0 + la) * 64 + (hi ? 8 : 0);
    f16x8 qf[4];
#pragma unroll
    for (int kd = 0; kd < 4; kd++) qf[kd] = *(const f16x8*)&Qg[kd * 16];

    f32x16 oacc[2] = {};
    float rm = -1e30f, rl = 0.f;

    const unsigned short* Kl = kb + (long)(b * HKV_ + g) * T_ * 64 + (long)la * 64 + (hi ? 8 : 0);
    const unsigned short* Vl = vt + (long)(b * HKV_ + g) * 64 * T_ + (long)la * T_ + (hi ? 8 : 0);

    // peel: K A-fragments for tile 0: row=key = tau*32+la, k(d)=kd*16+hi*8+i
    f16x8 kf[2][4];
#pragma unroll
    for (int tau = 0; tau < 2; tau++)
#pragma unroll
        for (int kd = 0; kd < 4; kd++)
            kf[tau][kd] = *(const f16x8*)&Kl[(long)(tau * 32) * 64 + kd * 16];

    for (int kt = 0; kt < 32; ++kt) {
        // ---- S^T = mfma(K, Q): C[key][query], col=query=la, row-keys lane-local
        f32x16 sacc[2] = {};
#pragma unroll
        for (int tau = 0; tau < 2; tau++)
#pragma unroll
            for (int kd = 0; kd < 4; kd++)
                sacc[tau] = __builtin_amdgcn_mfma_f32_32x32x16_f16(kf[tau][kd], qf[kd], sacc[tau], 0, 0, 0);
        // ---- V^T A-fragments for THIS tile (latency covered by softmax)
        f16x8 vf[2][4];
#pragma unroll
        for (int dt = 0; dt < 2; dt++)
#pragma unroll
            for (int kp = 0; kp < 4; kp++)
                vf[dt][kp] = *(const f16x8*)&Vl[(long)dt * 32 * T_ + kt * 64 + kp * 16];
        // ---- K fragments for NEXT tile
        {
            int ktn = (kt < 31) ? kt + 1 : kt;
#pragma unroll
            for (int tau = 0; tau < 2; tau++)
#pragma unroll
                for (int kd = 0; kd < 4; kd++)
                    kf[tau][kd] = *(const f16x8*)&Kl[((long)ktn * 64 + tau * 32) * 64 + kd * 16];
        }
        // ---- softmax (per-lane scalar; keys of this lane: 32 of 64, partner holds the rest)
        float pmax = sacc[0][0];
#pragma unroll
        for (int r = 1; r < 16; r++) pmax = fmaxf(pmax, sacc[0][r]);
#pragma unroll
        for (int r = 0; r < 16; r++) pmax = fmaxf(pmax, sacc[1][r]);
        pmax = fmaxf(pmax, __shfl_xor(pmax, 32, 64));
        float mnew = fmaxf(rm, pmax);
        float corr = __builtin_amdgcn_exp2f(rm - mnew);
        rm = mnew;
        float rs = 0.f;
        unsigned int pka[2][8];
#pragma unroll
        for (int tau = 0; tau < 2; tau++)
#pragma unroll
            for (int r = 0; r < 8; r++) {
                float p0 = __builtin_amdgcn_exp2f(sacc[tau][2 * r]     - mnew);
                float p1 = __builtin_amdgcn_exp2f(sacc[tau][2 * r + 1] - mnew);
                rs += p0 + p1;
                pka[tau][r] = __builtin_bit_cast(unsigned int, __builtin_amdgcn_cvt_pkrtz(p0, p1));
            }
        rl = rl * corr + rs;
#pragma unroll
        for (int dt = 0; dt < 2; dt++) oacc[dt] = oacc[dt] * corr;
        // ---- P cross-half exchange: 4 predicated shuffles per ktile
        // own pair r covers keys base_r + 4*hi, base = {0,2,8,10,16,18,24,26}[r] (+32*tau)
        // hi=0 needs partner r{0,1,4,5}; hi=1 needs partner r{2,3,6,7}
        unsigned int recv[2][4];
#pragma unroll
        for (int tau = 0; tau < 2; tau++) {
#pragma unroll
            for (int s = 0; s < 4; s++) {
                const int aidx[4] = {0, 1, 4, 5};
                const int bidx[4] = {2, 3, 6, 7};
                unsigned int send = hi ? pka[tau][aidx[s]] : pka[tau][bidx[s]];
                recv[tau][s] = __shfl_xor((int)send, 32, 64);
            }
        }
        // ---- assemble P B-fragments (col=query=la, k=key) and PV
#pragma unroll
        for (int kp = 0; kp < 4; kp++) {
            const int tau = kp >> 1, u = (kp & 1) * 4, e = (kp & 1) * 2;
            union { unsigned int wd[4]; f16x8 v; } pf;
            pf.wd[0] = hi ? recv[tau][e]     : pka[tau][u];
            pf.wd[1] = hi ? recv[tau][e + 1] : pka[tau][u + 1];
            pf.wd[2] = hi ? pka[tau][u + 2]  : recv[tau][e];
            pf.wd[3] = hi ? pka[tau][u + 3]  : recv[tau][e + 1];
#pragma unroll
            for (int dt = 0; dt < 2; dt++)
                oacc[dt] = __builtin_amdgcn_mfma_f32_32x32x16_f16(vf[dt][kp], pf.v, oacc[dt], 0, 0, 0);
        }
    }
    // ---- epilogue: O^T[d][query=la]; d = dt*32 + (reg&3) + 8*(reg>>2) + 4*hi
    float tot = rl + __shfl_xor(rl, 32, 64);
    float inv = 1.0f / tot;
    long t = qt0 + la;
    unsigned short* aor = ao + (long)(b * T_ + t) * D_ + h * 64 + (hi ? 4 : 0);
#pragma unroll
    for (int dt = 0; dt < 2; dt++)
#pragma unroll
        for (int r4 = 0; r4 < 4; r4++) {
            unsigned long long pk;
            pk  = (unsigned long long)f2h(oacc[dt][4 * r4 + 0] * inv);
            pk |= (unsigned long long)f2h(oacc[dt][4 * r4 + 1] * inv) << 16;
            pk |= (unsigned long long)f2h(oacc[dt][4 * r4 + 2] * inv) << 32;
            pk |= (unsigned long long)f2h(oacc[dt][4 * r4 + 3] * inv) << 48;
            *(unsigned long long*)&aor[dt * 32 + 8 * r4] = pk;
        }
}

// ---------------------------------------------------------------- launch
extern "C" void kernel_launch(void* const* d_in, const int* in_sizes, int n_in,
                              void* d_out, int out_size, void* d_ws, size_t ws_size,
                              hipStream_t stream) {
    const float* x    = (const float*)d_in[0];
    const float* cosb = (const float*)d_in[1];
    const float* sinb = (const float*)d_in[2];
    const float* Wq   = (const float*)d_in[3];
    const float* Wkv  = (const float*)d_in[4];
    const float* Wo   = (const float*)d_in[5];
    float* out = (float*)d_out;

    char* ws = (char*)d_ws;
    unsigned short* xb   = (unsigned short*)(ws);              // reused as attnout
    unsigned short* wcat = (unsigned short*)(ws + 16777216);   // [Wq ; Wkv]
    unsigned short* wob  = (unsigned short*)(ws + 19922944);
    unsigned short* qkvb = (unsigned short*)(ws + 22020096);
    unsigned short* qsb  = (unsigned short*)(ws + 47185920);
    unsigned short* vtb  = (unsigned short*)(ws + 63963136);
    unsigned short* kbuf = (unsigned short*)(ws + 68157440);

    k_cast<<<2048, 256, 0, stream>>>(x,   xb,             (B_ * T_ * D_) / 4);
    k_cast<<<1024, 256, 0, stream>>>(Wq,  wcat,           (D_ * D_) / 4);
    k_cast<<<512,  256, 0, stream>>>(Wkv, wcat + D_ * D_, (512 * D_) / 4);
    k_cast<<<1024, 256, 0, stream>>>(Wo,  wob,            (D_ * D_) / 4);

    k_gemm_bt<true><<<dim3(NQKV_ / 128, (B_ * T_) / 128), 256, 0, stream>>>(xb, wcat, qkvb, B_ * T_, NQKV_, D_);
    k_rope<<<B_ * (T_ / 64), 256, 0, stream>>>(qkvb, cosb, sinb, qsb, kbuf, vtb);
    k_attn<<<dim3(T_ / 128, B_ * HQ_), 256, 0, stream>>>(qsb, kbuf, vtb, xb);
    k_gemm_bt<false><<<dim3(D_ / 128, (B_ * T_) / 128), 256, 0, stream>>>(xb, wob, out, B_ * T_, D_, D_);
}

// Round 11
// 256.191 us; speedup vs baseline: 1.4322x; 1.4118x over previous
//
#include <hip/hip_runtime.h>
#include <hip/hip_bf16.h>

#define B_   4
#define T_   2048
#define D_   1024
#define HQ_  16
#define HKV_ 4
#define HD_  64
#define NQKV_ 1536

typedef __attribute__((ext_vector_type(4))) float f32x4;
typedef __attribute__((ext_vector_type(16))) float f32x16;
typedef _Float16 f16x8 __attribute__((ext_vector_type(8)));
typedef __attribute__((ext_vector_type(8))) unsigned short u16x8;

static __device__ __forceinline__ float h2f(unsigned short u) {
    union { unsigned short u; _Float16 h; } c; c.u = u; return (float)c.h;
}
static __device__ __forceinline__ unsigned short f2h(float f) {
    union { _Float16 h; unsigned short u; } c; c.h = (_Float16)f; return c.u;
}

#define GLL16(gsrc, ldst) \
    __builtin_amdgcn_global_load_lds((const __attribute__((address_space(1))) unsigned int*)(gsrc), \
                                     (__attribute__((address_space(3))) unsigned int*)(ldst), 16, 0, 0)

// ---------------------------------------------------------------- cast f32->f16
__global__ __launch_bounds__(256) void k_cast(const float* __restrict__ in,
                                              unsigned short* __restrict__ out, int n4) {
    int i = blockIdx.x * blockDim.x + threadIdx.x;
    int stride = gridDim.x * blockDim.x;
    for (; i < n4; i += stride) {
        f32x4 v = ((const f32x4*)in)[i];
        unsigned long long r;
        r  = (unsigned long long)f2h(v.x);
        r |= (unsigned long long)f2h(v.y) << 16;
        r |= (unsigned long long)f2h(v.z) << 32;
        r |= (unsigned long long)f2h(v.w) << 48;
        ((unsigned long long*)out)[i] = r;
    }
}

// ---------------------------------------------------------------- GEMM  C = A(MxK) * B(NxK)^T  (verified)
template <bool F16OUT>
__global__ __launch_bounds__(256) void k_gemm_bt(const unsigned short* __restrict__ A,
                                                 const unsigned short* __restrict__ Bw,
                                                 void* __restrict__ Cv, int M, int N, int K) {
    __shared__ __attribute__((aligned(16))) unsigned short As[128 * 32];
    __shared__ __attribute__((aligned(16))) unsigned short Bs[128 * 32];
    const int tid = threadIdx.x;
    const int w = tid >> 6, lane = tid & 63;
    const int gq = lane >> 4, n16 = lane & 15;
    const long gm0 = (long)blockIdx.y * 128, gn0 = (long)blockIdx.x * 128;
    const int wm = (w >> 1) * 64, wn = (w & 1) * 64;

    f32x4 acc[4][4] = {};

    const int KT = K >> 5;
    const int srow0 = w * 32 + (lane >> 2);
    unsigned short* alds = &As[w * 1024];
    unsigned short* blds = &Bs[w * 1024];

    auto stage = [&](int kt) {
        const int k0 = kt * 32;
#pragma unroll
        for (int i = 0; i < 2; i++) {
            int row = srow0 + i * 16;
            int chk = (lane & 3) ^ ((row >> 1) & 3);
            GLL16(A  + (gm0 + row) * K + k0 + chk * 8, alds + i * 512);
            GLL16(Bw + (gn0 + row) * K + k0 + chk * 8, blds + i * 512);
        }
    };

    stage(0);
    for (int kt = 0; kt < KT; ++kt) {
        __syncthreads();
        f16x8 af[4], bf[4];
#pragma unroll
        for (int mf = 0; mf < 4; mf++) {
            int row = wm + mf * 16 + n16;
            int chk = gq ^ ((row >> 1) & 3);
            af[mf] = *(const f16x8*)&As[row * 32 + chk * 8];
        }
#pragma unroll
        for (int nf = 0; nf < 4; nf++) {
            int row = wn + nf * 16 + n16;
            int chk = gq ^ ((row >> 1) & 3);
            bf[nf] = *(const f16x8*)&Bs[row * 32 + chk * 8];
        }
#pragma unroll
        for (int mf = 0; mf < 4; mf++)
#pragma unroll
            for (int nf = 0; nf < 4; nf++)
                acc[mf][nf] = __builtin_amdgcn_mfma_f32_16x16x32_f16(af[mf], bf[nf], acc[mf][nf], 0, 0, 0);
        __syncthreads();
        if (kt + 1 < KT) stage(kt + 1);
    }

#pragma unroll
    for (int mf = 0; mf < 4; mf++)
#pragma unroll
        for (int nf = 0; nf < 4; nf++)
#pragma unroll
            for (int q = 0; q < 4; q++) {
                long r = gm0 + wm + mf * 16 + gq * 4 + q;
                long c = gn0 + wn + nf * 16 + n16;
                if (F16OUT)
                    ((unsigned short*)Cv)[r * N + c] = f2h(acc[mf][nf][q]);
                else
                    ((float*)Cv)[r * N + c] = acc[mf][nf][q];
            }
}

// ---------------------------------------------------------------- RoPE + scatter + V transpose (verified)
__global__ __launch_bounds__(256) void k_rope(const unsigned short* __restrict__ qkv,
                                              const float* __restrict__ cosb,
                                              const float* __restrict__ sinb,
                                              unsigned short* __restrict__ qs,
                                              unsigned short* __restrict__ kb,
                                              unsigned short* __restrict__ vt) {
    const int blk = blockIdx.x;
    const int b = blk >> 5;
    const int t0 = (blk & 31) * 64;
    const int tid = threadIdx.x;
    const float ALPHA = 0.125f * 1.44269504088896340736f; // HD^-0.5 * log2(e), folded into q

    for (int it = 0; it < 128; ++it) {
        int idx = it * 256 + tid;
        int p = idx & 511, tl = idx >> 9;
        int h = p >> 5, dp = p & 31;
        int t = t0 + tl;
        unsigned int v = *(const unsigned int*)&qkv[(long)(b * T_ + t) * NQKV_ + h * 64 + dp * 2];
        float q0 = h2f((unsigned short)v), q1 = h2f((unsigned short)(v >> 16));
        int d0 = dp * 2;
        float2 cc = *(const float2*)&cosb[t * 64 + d0];
        float2 ss = *(const float2*)&sinb[t * 64 + d0];
        float o0 = (q0 * cc.x - q1 * ss.x) * ALPHA;
        float o1 = (q1 * cc.y + q0 * ss.y) * ALPHA;
        unsigned int ov = (unsigned int)f2h(o0) | ((unsigned int)f2h(o1) << 16);
        *(unsigned int*)&qs[((long)(b * HQ_ + h) * T_ + t) * 64 + d0] = ov;
    }
    for (int it = 0; it < 32; ++it) {
        int idx = it * 256 + tid;
        int dp = idx & 31, g = (idx >> 5) & 3, tl = idx >> 7;
        int t = t0 + tl;
        unsigned int v = *(const unsigned int*)&qkv[(long)(b * T_ + t) * NQKV_ + 1024 + g * 128 + dp * 2];
        float k0 = h2f((unsigned short)v), k1 = h2f((unsigned short)(v >> 16));
        int d0 = dp * 2;
        float2 cc = *(const float2*)&cosb[t * 64 + d0];
        float2 ss = *(const float2*)&sinb[t * 64 + d0];
        float o0 = k0 * cc.x - k1 * ss.x;
        float o1 = k1 * cc.y + k0 * ss.y;
        unsigned int ov = (unsigned int)f2h(o0) | ((unsigned int)f2h(o1) << 16);
        *(unsigned int*)&kb[((long)(b * HKV_ + g) * T_ + t) * 64 + d0] = ov;
    }
    // V transpose: [t][d] -> [d][t]
    for (int it = 0; it < 8; ++it) {
        int idx = it * 256 + tid;
        int d = idx & 63, tc = (idx >> 6) & 7, g = idx >> 9;
        u16x8 vv;
#pragma unroll
        for (int j = 0; j < 8; ++j) {
            int t = t0 + tc * 8 + j;
            vv[j] = qkv[(long)(b * T_ + t) * NQKV_ + 1024 + g * 128 + 64 + d];
        }
        *(u16x8*)&vt[((long)(b * HKV_ + g) * 64 + d) * T_ + t0 + tc * 8] = vv;
    }
}

// ---------------------------------------------------------------- flash attention — swapped 32x32 + LDS staging
// 4 waves share each (kt) K/V tile: staged ONCE per block (coalesced), read as swizzled ds_read_b128.
// K: GLL16 pre-swizzle (round-5-verified). V^T: reg-stage (verified addrs) + swizzled ds_write (T14 split).
// Softmax per-lane scalar; P in-register (cvt_pkrtz + shfl exchange). Double-buffered, 1 barrier/tile.
__global__ __launch_bounds__(256) void k_attn(const unsigned short* __restrict__ qs,
                                              const unsigned short* __restrict__ kb,
                                              const unsigned short* __restrict__ vt,
                                              unsigned short* __restrict__ ao) {
    __shared__ __attribute__((aligned(16))) unsigned short Ks[2][64 * 64];
    __shared__ __attribute__((aligned(16))) unsigned short Vs[2][64 * 64];
    const int tid = threadIdx.x;
    const int w = tid >> 6, lane = tid & 63;
    const int la = lane & 31;
    const bool hi = (lane >> 5) != 0;
    const int bh = blockIdx.y;
    const int b = bh >> 4, h = bh & 15, g = h >> 2;
    const int qt0 = blockIdx.x * 128 + w * 32;

    // Q B-fragments: col=query=la, k(d) = kd*16 + hi*8 + i
    const unsigned short* Qg = qs + ((long)(b * HQ_ + h) * T_ + qt0 + la) * 64 + (hi ? 8 : 0);
    f16x8 qf[4];
#pragma unroll
    for (int kd = 0; kd < 4; kd++) qf[kd] = *(const f16x8*)&Qg[kd * 16];

    f32x16 oacc[2] = {};
    float rm = -1e30f, rl = 0.f;

    const unsigned short* Kg = kb + (long)(b * HKV_ + g) * T_ * 64;  // [key][d]
    const unsigned short* Vg = vt + (long)(b * HKV_ + g) * 64 * T_;  // [d][t]

    // --- K staging (round-5-verified GLL16 pattern): wave w stages rows w*16..w*16+15
    const int strow0 = w * 16 + (lane >> 3);
    const int schk = lane & 7;
    auto stageK = [&](int kt, int buf) {
        unsigned short* klds = &Ks[buf][w * 1024];
#pragma unroll
        for (int i = 0; i < 2; i++) {
            int row = strow0 + i * 8;
            int chk = schk ^ (row & 7);
            GLL16(Kg + (long)(kt * 64 + row) * 64 + chk * 8, klds + i * 512);
        }
    };
    // --- V staging: thread t handles row vrow, chunks vc0 and vc0+4 (coalesced 16B reads)
    const int vrow = tid >> 2;
    const int vc0 = tid & 3;
    const unsigned short* Vrow = Vg + (long)vrow * T_;
    const int vw0 = vrow * 64 + ((vc0)     ^ (vrow & 7)) * 8;  // swizzled LDS dests
    const int vw1 = vrow * 64 + ((vc0 + 4) ^ (vrow & 7)) * 8;

    // prologue: stage tile 0 into buf 0
    stageK(0, 0);
    {
        u16x8 a = *(const u16x8*)&Vrow[vc0 * 8];
        u16x8 c = *(const u16x8*)&Vrow[(vc0 + 4) * 8];
        *(u16x8*)&Vs[0][vw0] = a;
        *(u16x8*)&Vs[0][vw1] = c;
    }

    const int lx = la & 7;
    int cur = 0;
    for (int kt = 0; kt < 32; ++kt) {
        __syncthreads();   // drains GLL16 (vmcnt) + V ds_writes (lgkm) for buf[cur]
        const int nxt = cur ^ 1;
        const int ktn = (kt < 31) ? kt + 1 : 31;
        // ---- issue next tile staging first (max latency cover)
        stageK(ktn, nxt);
        u16x8 nv0 = *(const u16x8*)&Vrow[ktn * 64 + vc0 * 8];
        u16x8 nv1 = *(const u16x8*)&Vrow[ktn * 64 + (vc0 + 4) * 8];
        // ---- fragment reads from buf[cur] (swizzled ds_read_b128)
        f16x8 kf[2][4], vf[2][4];
#pragma unroll
        for (int tau = 0; tau < 2; tau++)
#pragma unroll
            for (int kd = 0; kd < 4; kd++)
                kf[tau][kd] = *(const f16x8*)&Ks[cur][(tau * 32 + la) * 64 + ((kd * 2 + (int)hi) ^ lx) * 8];
#pragma unroll
        for (int dt = 0; dt < 2; dt++)
#pragma unroll
            for (int kp = 0; kp < 4; kp++)
                vf[dt][kp] = *(const f16x8*)&Vs[cur][(dt * 32 + la) * 64 + ((kp * 2 + (int)hi) ^ lx) * 8];
        // ---- S^T = mfma(K, Q)
        f32x16 sacc[2] = {};
#pragma unroll
        for (int tau = 0; tau < 2; tau++)
#pragma unroll
            for (int kd = 0; kd < 4; kd++)
                sacc[tau] = __builtin_amdgcn_mfma_f32_32x32x16_f16(kf[tau][kd], qf[kd], sacc[tau], 0, 0, 0);
        // ---- softmax (per-lane scalar; tree max)
        float tm[16];
#pragma unroll
        for (int r = 0; r < 16; r++) tm[r] = fmaxf(sacc[0][r], sacc[1][r]);
#pragma unroll
        for (int st = 8; st > 0; st >>= 1)
#pragma unroll
            for (int r = 0; r < st; r++) tm[r] = fmaxf(tm[r], tm[r + st]);
        float pmax = fmaxf(tm[0], __shfl_xor(tm[0], 32, 64));
        float mnew = fmaxf(rm, pmax);
        float corr = __builtin_amdgcn_exp2f(rm - mnew);
        rm = mnew;
        float rs0 = 0.f, rs1 = 0.f;
        unsigned int pka[2][8];
#pragma unroll
        for (int tau = 0; tau < 2; tau++)
#pragma unroll
            for (int r = 0; r < 8; r++) {
                float p0 = __builtin_amdgcn_exp2f(sacc[tau][2 * r]     - mnew);
                float p1 = __builtin_amdgcn_exp2f(sacc[tau][2 * r + 1] - mnew);
                rs0 += p0; rs1 += p1;
                pka[tau][r] = __builtin_bit_cast(unsigned int, __builtin_amdgcn_cvt_pkrtz(p0, p1));
            }
        rl = rl * corr + (rs0 + rs1);
#pragma unroll
        for (int dt = 0; dt < 2; dt++) oacc[dt] = oacc[dt] * corr;
        // ---- P cross-half exchange (4 shuffles per tau)
        unsigned int recv[2][4];
#pragma unroll
        for (int tau = 0; tau < 2; tau++) {
#pragma unroll
            for (int s = 0; s < 4; s++) {
                const int aidx[4] = {0, 1, 4, 5};
                const int bidx[4] = {2, 3, 6, 7};
                unsigned int send = hi ? pka[tau][aidx[s]] : pka[tau][bidx[s]];
                recv[tau][s] = __shfl_xor((int)send, 32, 64);
            }
        }
        // ---- assemble P B-fragments and PV
#pragma unroll
        for (int kp = 0; kp < 4; kp++) {
            const int tau = kp >> 1, u = (kp & 1) * 4, e = (kp & 1) * 2;
            union { unsigned int wd[4]; f16x8 v; } pf;
            pf.wd[0] = hi ? recv[tau][e]     : pka[tau][u];
            pf.wd[1] = hi ? recv[tau][e + 1] : pka[tau][u + 1];
            pf.wd[2] = hi ? pka[tau][u + 2]  : recv[tau][e];
            pf.wd[3] = hi ? pka[tau][u + 3]  : recv[tau][e + 1];
#pragma unroll
            for (int dt = 0; dt < 2; dt++)
                oacc[dt] = __builtin_amdgcn_mfma_f32_32x32x16_f16(vf[dt][kp], pf.v, oacc[dt], 0, 0, 0);
        }
        // ---- V ds_writes for next tile (loads have had the whole tile to land)
        *(u16x8*)&Vs[nxt][vw0] = nv0;
        *(u16x8*)&Vs[nxt][vw1] = nv1;
        cur = nxt;
    }
    // ---- epilogue: O^T[d][query=la]; d = dt*32 + (reg&3) + 8*(reg>>2) + 4*hi
    float tot = rl + __shfl_xor(rl, 32, 64);
    float inv = 1.0f / tot;
    long t = qt0 + la;
    unsigned short* aor = ao + (long)(b * T_ + t) * D_ + h * 64 + (hi ? 4 : 0);
#pragma unroll
    for (int dt = 0; dt < 2; dt++)
#pragma unroll
        for (int r4 = 0; r4 < 4; r4++) {
            unsigned long long pk;
            pk  = (unsigned long long)f2h(oacc[dt][4 * r4 + 0] * inv);
            pk |= (unsigned long long)f2h(oacc[dt][4 * r4 + 1] * inv) << 16;
            pk |= (unsigned long long)f2h(oacc[dt][4 * r4 + 2] * inv) << 32;
            pk |= (unsigned long long)f2h(oacc[dt][4 * r4 + 3] * inv) << 48;
            *(unsigned long long*)&aor[dt * 32 + 8 * r4] = pk;
        }
}

// ---------------------------------------------------------------- launch
extern "C" void kernel_launch(void* const* d_in, const int* in_sizes, int n_in,
                              void* d_out, int out_size, void* d_ws, size_t ws_size,
                              hipStream_t stream) {
    const float* x    = (const float*)d_in[0];
    const float* cosb = (const float*)d_in[1];
    const float* sinb = (const float*)d_in[2];
    const float* Wq   = (const float*)d_in[3];
    const float* Wkv  = (const float*)d_in[4];
    const float* Wo   = (const float*)d_in[5];
    float* out = (float*)d_out;

    char* ws = (char*)d_ws;
    unsigned short* xb   = (unsigned short*)(ws);              // reused as attnout
    unsigned short* wcat = (unsigned short*)(ws + 16777216);   // [Wq ; Wkv]
    unsigned short* wob  = (unsigned short*)(ws + 19922944);
    unsigned short* qkvb = (unsigned short*)(ws + 22020096);
    unsigned short* qsb  = (unsigned short*)(ws + 47185920);
    unsigned short* vtb  = (unsigned short*)(ws + 63963136);
    unsigned short* kbuf = (unsigned short*)(ws + 68157440);

    k_cast<<<2048, 256, 0, stream>>>(x,   xb,             (B_ * T_ * D_) / 4);
    k_cast<<<1024, 256, 0, stream>>>(Wq,  wcat,           (D_ * D_) / 4);
    k_cast<<<512,  256, 0, stream>>>(Wkv, wcat + D_ * D_, (512 * D_) / 4);
    k_cast<<<1024, 256, 0, stream>>>(Wo,  wob,            (D_ * D_) / 4);

    k_gemm_bt<true><<<dim3(NQKV_ / 128, (B_ * T_) / 128), 256, 0, stream>>>(xb, wcat, qkvb, B_ * T_, NQKV_, D_);
    k_rope<<<B_ * (T_ / 64), 256, 0, stream>>>(qkvb, cosb, sinb, qsb, kbuf, vtb);
    k_attn<<<dim3(T_ / 128, B_ * HQ_), 256, 0, stream>>>(qsb, kbuf, vtb, xb);
    k_gemm_bt<false><<<dim3(D_ / 128, (B_ * T_) / 128), 256, 0, stream>>>(xb, wob, out, B_ * T_, D_, D_);
}

// Round 12
// 245.032 us; speedup vs baseline: 1.4974x; 1.0455x over previous
//
#include <hip/hip_runtime.h>
#include <hip/hip_bf16.h>
#include <type_traits>

#define B_   4
#define T_   2048
#define D_   1024
#define HQ_  16
#define HKV_ 4
#define HD_  64
#define NQKV_ 1536

typedef __attribute__((ext_vector_type(4))) float f32x4;
typedef __attribute__((ext_vector_type(16))) float f32x16;
typedef _Float16 f16x8 __attribute__((ext_vector_type(8)));
typedef __attribute__((ext_vector_type(8))) unsigned short u16x8;

static __device__ __forceinline__ float h2f(unsigned short u) {
    union { unsigned short u; _Float16 h; } c; c.u = u; return (float)c.h;
}
static __device__ __forceinline__ unsigned short f2h(float f) {
    union { _Float16 h; unsigned short u; } c; c.h = (_Float16)f; return c.u;
}

#define GLL16(gsrc, ldst) \
    __builtin_amdgcn_global_load_lds((const __attribute__((address_space(1))) unsigned int*)(gsrc), \
                                     (__attribute__((address_space(3))) unsigned int*)(ldst), 16, 0, 0)

// ---------------------------------------------------------------- cast f32->f16
__global__ __launch_bounds__(256) void k_cast(const float* __restrict__ in,
                                              unsigned short* __restrict__ out, int n4) {
    int i = blockIdx.x * blockDim.x + threadIdx.x;
    int stride = gridDim.x * blockDim.x;
    for (; i < n4; i += stride) {
        f32x4 v = ((const f32x4*)in)[i];
        unsigned long long r;
        r  = (unsigned long long)f2h(v.x);
        r |= (unsigned long long)f2h(v.y) << 16;
        r |= (unsigned long long)f2h(v.z) << 32;
        r |= (unsigned long long)f2h(v.w) << 48;
        ((unsigned long long*)out)[i] = r;
    }
}

// ---------------------------------------------------------------- GEMM  C = A(MxK) * B(NxK)^T  (verified)
template <bool F16OUT>
__global__ __launch_bounds__(256) void k_gemm_bt(const unsigned short* __restrict__ A,
                                                 const unsigned short* __restrict__ Bw,
                                                 void* __restrict__ Cv, int M, int N, int K) {
    __shared__ __attribute__((aligned(16))) unsigned short As[128 * 32];
    __shared__ __attribute__((aligned(16))) unsigned short Bs[128 * 32];
    const int tid = threadIdx.x;
    const int w = tid >> 6, lane = tid & 63;
    const int gq = lane >> 4, n16 = lane & 15;
    const long gm0 = (long)blockIdx.y * 128, gn0 = (long)blockIdx.x * 128;
    const int wm = (w >> 1) * 64, wn = (w & 1) * 64;

    f32x4 acc[4][4] = {};

    const int KT = K >> 5;
    const int srow0 = w * 32 + (lane >> 2);
    unsigned short* alds = &As[w * 1024];
    unsigned short* blds = &Bs[w * 1024];

    auto stage = [&](int kt) {
        const int k0 = kt * 32;
#pragma unroll
        for (int i = 0; i < 2; i++) {
            int row = srow0 + i * 16;
            int chk = (lane & 3) ^ ((row >> 1) & 3);
            GLL16(A  + (gm0 + row) * K + k0 + chk * 8, alds + i * 512);
            GLL16(Bw + (gn0 + row) * K + k0 + chk * 8, blds + i * 512);
        }
    };

    stage(0);
    for (int kt = 0; kt < KT; ++kt) {
        __syncthreads();
        f16x8 af[4], bf[4];
#pragma unroll
        for (int mf = 0; mf < 4; mf++) {
            int row = wm + mf * 16 + n16;
            int chk = gq ^ ((row >> 1) & 3);
            af[mf] = *(const f16x8*)&As[row * 32 + chk * 8];
        }
#pragma unroll
        for (int nf = 0; nf < 4; nf++) {
            int row = wn + nf * 16 + n16;
            int chk = gq ^ ((row >> 1) & 3);
            bf[nf] = *(const f16x8*)&Bs[row * 32 + chk * 8];
        }
#pragma unroll
        for (int mf = 0; mf < 4; mf++)
#pragma unroll
            for (int nf = 0; nf < 4; nf++)
                acc[mf][nf] = __builtin_amdgcn_mfma_f32_16x16x32_f16(af[mf], bf[nf], acc[mf][nf], 0, 0, 0);
        __syncthreads();
        if (kt + 1 < KT) stage(kt + 1);
    }

#pragma unroll
    for (int mf = 0; mf < 4; mf++)
#pragma unroll
        for (int nf = 0; nf < 4; nf++)
#pragma unroll
            for (int q = 0; q < 4; q++) {
                long r = gm0 + wm + mf * 16 + gq * 4 + q;
                long c = gn0 + wn + nf * 16 + n16;
                if (F16OUT)
                    ((unsigned short*)Cv)[r * N + c] = f2h(acc[mf][nf][q]);
                else
                    ((float*)Cv)[r * N + c] = acc[mf][nf][q];
            }
}

// ---------------------------------------------------------------- RoPE + scatter + V transpose (verified)
__global__ __launch_bounds__(256) void k_rope(const unsigned short* __restrict__ qkv,
                                              const float* __restrict__ cosb,
                                              const float* __restrict__ sinb,
                                              unsigned short* __restrict__ qs,
                                              unsigned short* __restrict__ kb,
                                              unsigned short* __restrict__ vt) {
    const int blk = blockIdx.x;
    const int b = blk >> 5;
    const int t0 = (blk & 31) * 64;
    const int tid = threadIdx.x;
    const float ALPHA = 0.125f * 1.44269504088896340736f; // HD^-0.5 * log2(e), folded into q

    for (int it = 0; it < 128; ++it) {
        int idx = it * 256 + tid;
        int p = idx & 511, tl = idx >> 9;
        int h = p >> 5, dp = p & 31;
        int t = t0 + tl;
        unsigned int v = *(const unsigned int*)&qkv[(long)(b * T_ + t) * NQKV_ + h * 64 + dp * 2];
        float q0 = h2f((unsigned short)v), q1 = h2f((unsigned short)(v >> 16));
        int d0 = dp * 2;
        float2 cc = *(const float2*)&cosb[t * 64 + d0];
        float2 ss = *(const float2*)&sinb[t * 64 + d0];
        float o0 = (q0 * cc.x - q1 * ss.x) * ALPHA;
        float o1 = (q1 * cc.y + q0 * ss.y) * ALPHA;
        unsigned int ov = (unsigned int)f2h(o0) | ((unsigned int)f2h(o1) << 16);
        *(unsigned int*)&qs[((long)(b * HQ_ + h) * T_ + t) * 64 + d0] = ov;
    }
    for (int it = 0; it < 32; ++it) {
        int idx = it * 256 + tid;
        int dp = idx & 31, g = (idx >> 5) & 3, tl = idx >> 7;
        int t = t0 + tl;
        unsigned int v = *(const unsigned int*)&qkv[(long)(b * T_ + t) * NQKV_ + 1024 + g * 128 + dp * 2];
        float k0 = h2f((unsigned short)v), k1 = h2f((unsigned short)(v >> 16));
        int d0 = dp * 2;
        float2 cc = *(const float2*)&cosb[t * 64 + d0];
        float2 ss = *(const float2*)&sinb[t * 64 + d0];
        float o0 = k0 * cc.x - k1 * ss.x;
        float o1 = k1 * cc.y + k0 * ss.y;
        unsigned int ov = (unsigned int)f2h(o0) | ((unsigned int)f2h(o1) << 16);
        *(unsigned int*)&kb[((long)(b * HKV_ + g) * T_ + t) * 64 + d0] = ov;
    }
    // V transpose: [t][d] -> [d][t]
    for (int it = 0; it < 8; ++it) {
        int idx = it * 256 + tid;
        int d = idx & 63, tc = (idx >> 6) & 7, g = idx >> 9;
        u16x8 vv;
#pragma unroll
        for (int j = 0; j < 8; ++j) {
            int t = t0 + tc * 8 + j;
            vv[j] = qkv[(long)(b * T_ + t) * NQKV_ + 1024 + g * 128 + 64 + d];
        }
        *(u16x8*)&vt[((long)(b * HKV_ + g) * 64 + d) * T_ + t0 + tc * 8] = vv;
    }
}

// ---------------------------------------------------------------- flash attention — swapped 32x32 + LDS staging
// Round-11 structure (verified) + T13 defer-max (THR=8) + compile-time LDS offsets (unroll-2, hoisted swizzle).
__global__ __launch_bounds__(256) void k_attn(const unsigned short* __restrict__ qs,
                                              const unsigned short* __restrict__ kb,
                                              const unsigned short* __restrict__ vt,
                                              unsigned short* __restrict__ ao) {
    __shared__ __attribute__((aligned(16))) unsigned short Ks[2][64 * 64];
    __shared__ __attribute__((aligned(16))) unsigned short Vs[2][64 * 64];
    const int tid = threadIdx.x;
    const int w = tid >> 6, lane = tid & 63;
    const int la = lane & 31;
    const bool hi = (lane >> 5) != 0;
    const int bh = blockIdx.y;
    const int b = bh >> 4, h = bh & 15, g = h >> 2;
    const int qt0 = blockIdx.x * 128 + w * 32;

    // Q B-fragments: col=query=la, k(d) = kd*16 + hi*8 + i
    const unsigned short* Qg = qs + ((long)(b * HQ_ + h) * T_ + qt0 + la) * 64 + (hi ? 8 : 0);
    f16x8 qf[4];
#pragma unroll
    for (int kd = 0; kd < 4; kd++) qf[kd] = *(const f16x8*)&Qg[kd * 16];

    f32x16 oacc[2] = {};
    float rm = -1e30f, rl = 0.f;

    const unsigned short* Kg = kb + (long)(b * HKV_ + g) * T_ * 64;  // [key][d]
    const unsigned short* Vg = vt + (long)(b * HKV_ + g) * 64 * T_;  // [d][t]

    // --- K staging (verified GLL16 pre-swizzle): wave w stages rows w*16..w*16+15
    const int strow0 = w * 16 + (lane >> 3);
    const int schk = lane & 7;
    // --- V staging: thread handles row vrow, chunks vc0 / vc0+4
    const int vrow = tid >> 2;
    const int vc0 = tid & 3;
    const unsigned short* Vrow = Vg + (long)vrow * T_;
    const int vw0 = vrow * 64 + ((vc0)     ^ (vrow & 7)) * 8;
    const int vw1 = vrow * 64 + ((vc0 + 4) ^ (vrow & 7)) * 8;

    // hoisted swizzled chunk offsets (shared by K and V reads): element offset within a buffer half
    const int lx = la & 7;
    int rcb[4];
#pragma unroll
    for (int kd = 0; kd < 4; kd++) rcb[kd] = la * 64 + (((kd * 2 + (int)hi) ^ lx) * 8);

    // prologue: stage tile 0 into buf 0
    {
        unsigned short* klds = &Ks[0][w * 1024];
#pragma unroll
        for (int i = 0; i < 2; i++) {
            int row = strow0 + i * 8;
            int chk = schk ^ (row & 7);
            GLL16(Kg + (long)row * 64 + chk * 8, klds + i * 512);
        }
        u16x8 a = *(const u16x8*)&Vrow[vc0 * 8];
        u16x8 c = *(const u16x8*)&Vrow[(vc0 + 4) * 8];
        *(u16x8*)&Vs[0][vw0] = a;
        *(u16x8*)&Vs[0][vw1] = c;
    }

    auto tile = [&](int kt, auto bufc) {
        constexpr int buf = decltype(bufc)::value;
        constexpr int nxt = buf ^ 1;
        __syncthreads();   // staged buf visible; prior reads of nxt done
        const int ktn = (kt < 31) ? kt + 1 : 31;
        // ---- issue next-tile staging first (max latency cover)
        {
            unsigned short* klds = &Ks[nxt][w * 1024];
#pragma unroll
            for (int i = 0; i < 2; i++) {
                int row = strow0 + i * 8;
                int chk = schk ^ (row & 7);
                GLL16(Kg + ((long)ktn * 64 + row) * 64 + chk * 8, klds + i * 512);
            }
        }
        u16x8 nv0 = *(const u16x8*)&Vrow[ktn * 64 + vc0 * 8];
        u16x8 nv1 = *(const u16x8*)&Vrow[ktn * 64 + (vc0 + 4) * 8];
        // ---- fragment reads (literal buf/tau -> immediate offsets; hoisted vaddr)
        f16x8 kf[2][4], vf[2][4];
#pragma unroll
        for (int tau = 0; tau < 2; tau++)
#pragma unroll
            for (int kd = 0; kd < 4; kd++)
                kf[tau][kd] = *(const f16x8*)&Ks[buf][tau * 2048 + rcb[kd]];
#pragma unroll
        for (int dt = 0; dt < 2; dt++)
#pragma unroll
            for (int kp = 0; kp < 4; kp++)
                vf[dt][kp] = *(const f16x8*)&Vs[buf][dt * 2048 + rcb[kp]];
        // ---- S^T = mfma(K, Q)
        f32x16 sacc[2] = {};
#pragma unroll
        for (int tau = 0; tau < 2; tau++)
#pragma unroll
            for (int kd = 0; kd < 4; kd++)
                sacc[tau] = __builtin_amdgcn_mfma_f32_32x32x16_f16(kf[tau][kd], qf[kd], sacc[tau], 0, 0, 0);
        // ---- local max (tree, max3-friendly)
        float t8[8];
#pragma unroll
        for (int r = 0; r < 8; r++)
            t8[r] = fmaxf(fmaxf(sacc[0][r], sacc[0][r + 8]), fmaxf(sacc[1][r], sacc[1][r + 8]));
        float pmax = fmaxf(fmaxf(fmaxf(t8[0], t8[1]), fmaxf(t8[2], t8[3])),
                           fmaxf(fmaxf(t8[4], t8[5]), fmaxf(t8[6], t8[7])));
        // ---- T13 defer-max: rescale only when max grew past THR (wave-uniform branch)
        if (!__all(pmax - rm <= 8.0f)) {
            float pmaxx = fmaxf(pmax, __shfl_xor(pmax, 32, 64));
            float mnew = fmaxf(rm, pmaxx);
            float corr = __builtin_amdgcn_exp2f(rm - mnew);
            rm = mnew;
            rl *= corr;
#pragma unroll
            for (int dt = 0; dt < 2; dt++) oacc[dt] = oacc[dt] * corr;
        }
        // ---- P = exp2(S - rm), packed to f16
        float rs0 = 0.f, rs1 = 0.f;
        unsigned int pka[2][8];
#pragma unroll
        for (int tau = 0; tau < 2; tau++)
#pragma unroll
            for (int r = 0; r < 8; r++) {
                float p0 = __builtin_amdgcn_exp2f(sacc[tau][2 * r]     - rm);
                float p1 = __builtin_amdgcn_exp2f(sacc[tau][2 * r + 1] - rm);
                rs0 += p0; rs1 += p1;
                pka[tau][r] = __builtin_bit_cast(unsigned int, __builtin_amdgcn_cvt_pkrtz(p0, p1));
            }
        rl += rs0 + rs1;
        // ---- P cross-half exchange (4 shuffles per tau)
        unsigned int recv[2][4];
#pragma unroll
        for (int tau = 0; tau < 2; tau++) {
#pragma unroll
            for (int s = 0; s < 4; s++) {
                const int aidx[4] = {0, 1, 4, 5};
                const int bidx[4] = {2, 3, 6, 7};
                unsigned int send = hi ? pka[tau][aidx[s]] : pka[tau][bidx[s]];
                recv[tau][s] = __shfl_xor((int)send, 32, 64);
            }
        }
        // ---- assemble P B-fragments and PV
#pragma unroll
        for (int kp = 0; kp < 4; kp++) {
            const int tau = kp >> 1, u = (kp & 1) * 4, e = (kp & 1) * 2;
            union { unsigned int wd[4]; f16x8 v; } pf;
            pf.wd[0] = hi ? recv[tau][e]     : pka[tau][u];
            pf.wd[1] = hi ? recv[tau][e + 1] : pka[tau][u + 1];
            pf.wd[2] = hi ? pka[tau][u + 2]  : recv[tau][e];
            pf.wd[3] = hi ? pka[tau][u + 3]  : recv[tau][e + 1];
#pragma unroll
            for (int dt = 0; dt < 2; dt++)
                oacc[dt] = __builtin_amdgcn_mfma_f32_32x32x16_f16(vf[dt][kp], pf.v, oacc[dt], 0, 0, 0);
        }
        // ---- V ds_writes for next tile
        *(u16x8*)&Vs[nxt][vw0] = nv0;
        *(u16x8*)&Vs[nxt][vw1] = nv1;
    };

    for (int kt2 = 0; kt2 < 32; kt2 += 2) {
        tile(kt2,     std::integral_constant<int, 0>{});
        tile(kt2 + 1, std::integral_constant<int, 1>{});
    }

    // ---- epilogue: O^T[d][query=la]; d = dt*32 + (reg&3) + 8*(reg>>2) + 4*hi
    float tot = rl + __shfl_xor(rl, 32, 64);
    float inv = 1.0f / tot;
    long t = qt0 + la;
    unsigned short* aor = ao + (long)(b * T_ + t) * D_ + h * 64 + (hi ? 4 : 0);
#pragma unroll
    for (int dt = 0; dt < 2; dt++)
#pragma unroll
        for (int r4 = 0; r4 < 4; r4++) {
            unsigned long long pk;
            pk  = (unsigned long long)f2h(oacc[dt][4 * r4 + 0] * inv);
            pk |= (unsigned long long)f2h(oacc[dt][4 * r4 + 1] * inv) << 16;
            pk |= (unsigned long long)f2h(oacc[dt][4 * r4 + 2] * inv) << 32;
            pk |= (unsigned long long)f2h(oacc[dt][4 * r4 + 3] * inv) << 48;
            *(unsigned long long*)&aor[dt * 32 + 8 * r4] = pk;
        }
}

// ---------------------------------------------------------------- launch
extern "C" void kernel_launch(void* const* d_in, const int* in_sizes, int n_in,
                              void* d_out, int out_size, void* d_ws, size_t ws_size,
                              hipStream_t stream) {
    const float* x    = (const float*)d_in[0];
    const float* cosb = (const float*)d_in[1];
    const float* sinb = (const float*)d_in[2];
    const float* Wq   = (const float*)d_in[3];
    const float* Wkv  = (const float*)d_in[4];
    const float* Wo   = (const float*)d_in[5];
    float* out = (float*)d_out;

    char* ws = (char*)d_ws;
    unsigned short* xb   = (unsigned short*)(ws);              // reused as attnout
    unsigned short* wcat = (unsigned short*)(ws + 16777216);   // [Wq ; Wkv]
    unsigned short* wob  = (unsigned short*)(ws + 19922944);
    unsigned short* qkvb = (unsigned short*)(ws + 22020096);
    unsigned short* qsb  = (unsigned short*)(ws + 47185920);
    unsigned short* vtb  = (unsigned short*)(ws + 63963136);
    unsigned short* kbuf = (unsigned short*)(ws + 68157440);

    k_cast<<<2048, 256, 0, stream>>>(x,   xb,             (B_ * T_ * D_) / 4);
    k_cast<<<1024, 256, 0, stream>>>(Wq,  wcat,           (D_ * D_) / 4);
    k_cast<<<512,  256, 0, stream>>>(Wkv, wcat + D_ * D_, (512 * D_) / 4);
    k_cast<<<1024, 256, 0, stream>>>(Wo,  wob,            (D_ * D_) / 4);

    k_gemm_bt<true><<<dim3(NQKV_ / 128, (B_ * T_) / 128), 256, 0, stream>>>(xb, wcat, qkvb, B_ * T_, NQKV_, D_);
    k_rope<<<B_ * (T_ / 64), 256, 0, stream>>>(qkvb, cosb, sinb, qsb, kbuf, vtb);
    k_attn<<<dim3(T_ / 128, B_ * HQ_), 256, 0, stream>>>(qsb, kbuf, vtb, xb);
    k_gemm_bt<false><<<dim3(D_ / 128, (B_ * T_) / 128), 256, 0, stream>>>(xb, wob, out, B_ * T_, D_, D_);
}

// Round 13
// 203.966 us; speedup vs baseline: 1.7989x; 1.2013x over previous
//
#include <hip/hip_runtime.h>
#include <hip/hip_bf16.h>
#include <type_traits>

#define B_   4
#define T_   2048
#define D_   1024
#define HQ_  16
#define HKV_ 4
#define HD_  64
#define NQKV_ 1536

typedef __attribute__((ext_vector_type(4))) float f32x4;
typedef __attribute__((ext_vector_type(16))) float f32x16;
typedef _Float16 f16x8 __attribute__((ext_vector_type(8)));
typedef __attribute__((ext_vector_type(8))) unsigned short u16x8;

static __device__ __forceinline__ float h2f(unsigned short u) {
    union { unsigned short u; _Float16 h; } c; c.u = u; return (float)c.h;
}
static __device__ __forceinline__ unsigned short f2h(float f) {
    union { _Float16 h; unsigned short u; } c; c.h = (_Float16)f; return c.u;
}

#define GLL16(gsrc, ldst) \
    __builtin_amdgcn_global_load_lds((const __attribute__((address_space(1))) unsigned int*)(gsrc), \
                                     (__attribute__((address_space(3))) unsigned int*)(ldst), 16, 0, 0)

// ---------------------------------------------------------------- cast f32->f16
__global__ __launch_bounds__(256) void k_cast(const float* __restrict__ in,
                                              unsigned short* __restrict__ out, int n4) {
    int i = blockIdx.x * blockDim.x + threadIdx.x;
    int stride = gridDim.x * blockDim.x;
    for (; i < n4; i += stride) {
        f32x4 v = ((const f32x4*)in)[i];
        unsigned long long r;
        r  = (unsigned long long)f2h(v.x);
        r |= (unsigned long long)f2h(v.y) << 16;
        r |= (unsigned long long)f2h(v.z) << 32;
        r |= (unsigned long long)f2h(v.w) << 48;
        ((unsigned long long*)out)[i] = r;
    }
}

// ---------------------------------------------------------------- GEMM  C = A(MxK) * B(NxK)^T
// EPI=0: f32 store.  EPI=2: fused RoPE + Q/K/V scatter epilogue (writes qs/kb/vt directly).
// Both: XCD-aware tile swizzle (nwg % 8 == 0 -> bijective).
template <int EPI>
__global__ __launch_bounds__(256) void k_gemm_bt(const unsigned short* __restrict__ A,
                                                 const unsigned short* __restrict__ Bw,
                                                 void* __restrict__ Cv, int M, int N, int K,
                                                 const float* __restrict__ cosb = nullptr,
                                                 const float* __restrict__ sinb = nullptr,
                                                 unsigned short* __restrict__ qsp = nullptr,
                                                 unsigned short* __restrict__ kbp = nullptr,
                                                 unsigned short* __restrict__ vtp = nullptr) {
    __shared__ __attribute__((aligned(16))) unsigned short As[128 * 32];
    __shared__ __attribute__((aligned(16))) unsigned short Bs[128 * 32];
    const int tid = threadIdx.x;
    const int w = tid >> 6, lane = tid & 63;
    const int gq = lane >> 4, n16 = lane & 15;
    // XCD swizzle: HW round-robins linear id across 8 XCDs; give each XCD consecutive tiles.
    const int lid = blockIdx.y * gridDim.x + blockIdx.x;
    const int cpx = (gridDim.x * gridDim.y) >> 3;
    const int tilid = (lid & 7) * cpx + (lid >> 3);
    const int bx = tilid % gridDim.x, by = tilid / gridDim.x;
    const long gm0 = (long)by * 128, gn0 = (long)bx * 128;
    const int wm = (w >> 1) * 64, wn = (w & 1) * 64;

    f32x4 acc[4][4] = {};

    const int KT = K >> 5;
    const int srow0 = w * 32 + (lane >> 2);
    unsigned short* alds = &As[w * 1024];
    unsigned short* blds = &Bs[w * 1024];

    auto stage = [&](int kt) {
        const int k0 = kt * 32;
#pragma unroll
        for (int i = 0; i < 2; i++) {
            int row = srow0 + i * 16;
            int chk = (lane & 3) ^ ((row >> 1) & 3);
            GLL16(A  + (gm0 + row) * K + k0 + chk * 8, alds + i * 512);
            GLL16(Bw + (gn0 + row) * K + k0 + chk * 8, blds + i * 512);
        }
    };

    stage(0);
    for (int kt = 0; kt < KT; ++kt) {
        __syncthreads();
        f16x8 af[4], bf[4];
#pragma unroll
        for (int mf = 0; mf < 4; mf++) {
            int row = wm + mf * 16 + n16;
            int chk = gq ^ ((row >> 1) & 3);
            af[mf] = *(const f16x8*)&As[row * 32 + chk * 8];
        }
#pragma unroll
        for (int nf = 0; nf < 4; nf++) {
            int row = wn + nf * 16 + n16;
            int chk = gq ^ ((row >> 1) & 3);
            bf[nf] = *(const f16x8*)&Bs[row * 32 + chk * 8];
        }
#pragma unroll
        for (int mf = 0; mf < 4; mf++)
#pragma unroll
            for (int nf = 0; nf < 4; nf++)
                acc[mf][nf] = __builtin_amdgcn_mfma_f32_16x16x32_f16(af[mf], bf[nf], acc[mf][nf], 0, 0, 0);
        __syncthreads();
        if (kt + 1 < KT) stage(kt + 1);
    }

    if constexpr (EPI == 0) {
#pragma unroll
        for (int mf = 0; mf < 4; mf++)
#pragma unroll
            for (int nf = 0; nf < 4; nf++)
#pragma unroll
                for (int q = 0; q < 4; q++) {
                    long r = gm0 + wm + mf * 16 + gq * 4 + q;
                    long c = gn0 + wn + nf * 16 + n16;
                    ((float*)Cv)[r * N + c] = acc[mf][nf][q];
                }
    } else {
        // ---- fused RoPE + scatter. Column base wave-uniform, 64-aligned -> uniform Q/K/V branch.
        const float ALPHA = 0.125f * 1.44269504088896340736f; // HD^-0.5 * log2(e) (Q only)
        const int cbase = (int)gn0 + wn;
        const bool isQ = cbase < 1024;
        const int coff = cbase - 1024;
        const bool isV = (!isQ) && ((coff >> 6) & 1);
        const int g = isQ ? 0 : (coff >> 7);
#pragma unroll
        for (int mf = 0; mf < 4; mf++) {
            long r0 = gm0 + wm + mf * 16 + gq * 4;       // 4-aligned: never straddles a batch
            int b = (int)(r0 >> 11);
            int t0 = (int)(r0 & 2047);
#pragma unroll
            for (int nf = 0; nf < 4; nf++) {
                int c = cbase + nf * 16 + n16;
                int d = c & 63;
                if (isQ || !isV) {
                    // rope: partner column c^1 lives in lane n16^1 (same fragment element)
                    unsigned short* dst = isQ
                        ? qsp + ((long)(b * HQ_ + (c >> 6)) * T_ + t0) * 64 + d
                        : kbp + ((long)(b * HKV_ + g) * T_ + t0) * 64 + d;
                    const float sc = isQ ? ALPHA : 1.0f;
#pragma unroll
                    for (int q = 0; q < 4; q++) {
                        float v = acc[mf][nf][q];
                        float p = __shfl_xor(v, 1, 64);
                        float cc = cosb[(t0 + q) * 64 + d];
                        float sn = sinb[(t0 + q) * 64 + d];
                        float o = (d & 1) ? (v * cc + p * sn) : (v * cc - p * sn);
                        dst[(long)q * 64] = f2h(o * sc);
                    }
                } else {
                    // V: transpose-scatter, 4 consecutive t -> one u64 store
                    unsigned long long pk = 0;
#pragma unroll
                    for (int q = 0; q < 4; q++)
                        pk |= (unsigned long long)f2h(acc[mf][nf][q]) << (16 * q);
                    *(unsigned long long*)&vtp[((long)(b * HKV_ + g) * 64 + d) * T_ + t0] = pk;
                }
            }
        }
    }
}

// ---------------------------------------------------------------- flash attention — swapped 32x32 + LDS staging
// (round-12 verified: T13 defer-max, compile-time LDS offsets, double-buffer, in-register P)
__global__ __launch_bounds__(256) void k_attn(const unsigned short* __restrict__ qs,
                                              const unsigned short* __restrict__ kb,
                                              const unsigned short* __restrict__ vt,
                                              unsigned short* __restrict__ ao) {
    __shared__ __attribute__((aligned(16))) unsigned short Ks[2][64 * 64];
    __shared__ __attribute__((aligned(16))) unsigned short Vs[2][64 * 64];
    const int tid = threadIdx.x;
    const int w = tid >> 6, lane = tid & 63;
    const int la = lane & 31;
    const bool hi = (lane >> 5) != 0;
    const int bh = blockIdx.y;
    const int b = bh >> 4, h = bh & 15, g = h >> 2;
    const int qt0 = blockIdx.x * 128 + w * 32;

    const unsigned short* Qg = qs + ((long)(b * HQ_ + h) * T_ + qt0 + la) * 64 + (hi ? 8 : 0);
    f16x8 qf[4];
#pragma unroll
    for (int kd = 0; kd < 4; kd++) qf[kd] = *(const f16x8*)&Qg[kd * 16];

    f32x16 oacc[2] = {};
    float rm = -1e30f, rl = 0.f;

    const unsigned short* Kg = kb + (long)(b * HKV_ + g) * T_ * 64;
    const unsigned short* Vg = vt + (long)(b * HKV_ + g) * 64 * T_;

    const int strow0 = w * 16 + (lane >> 3);
    const int schk = lane & 7;
    const int vrow = tid >> 2;
    const int vc0 = tid & 3;
    const unsigned short* Vrow = Vg + (long)vrow * T_;
    const int vw0 = vrow * 64 + ((vc0)     ^ (vrow & 7)) * 8;
    const int vw1 = vrow * 64 + ((vc0 + 4) ^ (vrow & 7)) * 8;

    const int lx = la & 7;
    int rcb[4];
#pragma unroll
    for (int kd = 0; kd < 4; kd++) rcb[kd] = la * 64 + (((kd * 2 + (int)hi) ^ lx) * 8);

    {
        unsigned short* klds = &Ks[0][w * 1024];
#pragma unroll
        for (int i = 0; i < 2; i++) {
            int row = strow0 + i * 8;
            int chk = schk ^ (row & 7);
            GLL16(Kg + (long)row * 64 + chk * 8, klds + i * 512);
        }
        u16x8 a = *(const u16x8*)&Vrow[vc0 * 8];
        u16x8 c = *(const u16x8*)&Vrow[(vc0 + 4) * 8];
        *(u16x8*)&Vs[0][vw0] = a;
        *(u16x8*)&Vs[0][vw1] = c;
    }

    auto tile = [&](int kt, auto bufc) {
        constexpr int buf = decltype(bufc)::value;
        constexpr int nxt = buf ^ 1;
        __syncthreads();
        const int ktn = (kt < 31) ? kt + 1 : 31;
        {
            unsigned short* klds = &Ks[nxt][w * 1024];
#pragma unroll
            for (int i = 0; i < 2; i++) {
                int row = strow0 + i * 8;
                int chk = schk ^ (row & 7);
                GLL16(Kg + ((long)ktn * 64 + row) * 64 + chk * 8, klds + i * 512);
            }
        }
        u16x8 nv0 = *(const u16x8*)&Vrow[ktn * 64 + vc0 * 8];
        u16x8 nv1 = *(const u16x8*)&Vrow[ktn * 64 + (vc0 + 4) * 8];
        f16x8 kf[2][4], vf[2][4];
#pragma unroll
        for (int tau = 0; tau < 2; tau++)
#pragma unroll
            for (int kd = 0; kd < 4; kd++)
                kf[tau][kd] = *(const f16x8*)&Ks[buf][tau * 2048 + rcb[kd]];
#pragma unroll
        for (int dt = 0; dt < 2; dt++)
#pragma unroll
            for (int kp = 0; kp < 4; kp++)
                vf[dt][kp] = *(const f16x8*)&Vs[buf][dt * 2048 + rcb[kp]];
        f32x16 sacc[2] = {};
#pragma unroll
        for (int tau = 0; tau < 2; tau++)
#pragma unroll
            for (int kd = 0; kd < 4; kd++)
                sacc[tau] = __builtin_amdgcn_mfma_f32_32x32x16_f16(kf[tau][kd], qf[kd], sacc[tau], 0, 0, 0);
        float t8[8];
#pragma unroll
        for (int r = 0; r < 8; r++)
            t8[r] = fmaxf(fmaxf(sacc[0][r], sacc[0][r + 8]), fmaxf(sacc[1][r], sacc[1][r + 8]));
        float pmax = fmaxf(fmaxf(fmaxf(t8[0], t8[1]), fmaxf(t8[2], t8[3])),
                           fmaxf(fmaxf(t8[4], t8[5]), fmaxf(t8[6], t8[7])));
        if (!__all(pmax - rm <= 8.0f)) {
            float pmaxx = fmaxf(pmax, __shfl_xor(pmax, 32, 64));
            float mnew = fmaxf(rm, pmaxx);
            float corr = __builtin_amdgcn_exp2f(rm - mnew);
            rm = mnew;
            rl *= corr;
#pragma unroll
            for (int dt = 0; dt < 2; dt++) oacc[dt] = oacc[dt] * corr;
        }
        float rs0 = 0.f, rs1 = 0.f;
        unsigned int pka[2][8];
#pragma unroll
        for (int tau = 0; tau < 2; tau++)
#pragma unroll
            for (int r = 0; r < 8; r++) {
                float p0 = __builtin_amdgcn_exp2f(sacc[tau][2 * r]     - rm);
                float p1 = __builtin_amdgcn_exp2f(sacc[tau][2 * r + 1] - rm);
                rs0 += p0; rs1 += p1;
                pka[tau][r] = __builtin_bit_cast(unsigned int, __builtin_amdgcn_cvt_pkrtz(p0, p1));
            }
        rl += rs0 + rs1;
        unsigned int recv[2][4];
#pragma unroll
        for (int tau = 0; tau < 2; tau++) {
#pragma unroll
            for (int s = 0; s < 4; s++) {
                const int aidx[4] = {0, 1, 4, 5};
                const int bidx[4] = {2, 3, 6, 7};
                unsigned int send = hi ? pka[tau][aidx[s]] : pka[tau][bidx[s]];
                recv[tau][s] = __shfl_xor((int)send, 32, 64);
            }
        }
#pragma unroll
        for (int kp = 0; kp < 4; kp++) {
            const int tau = kp >> 1, u = (kp & 1) * 4, e = (kp & 1) * 2;
            union { unsigned int wd[4]; f16x8 v; } pf;
            pf.wd[0] = hi ? recv[tau][e]     : pka[tau][u];
            pf.wd[1] = hi ? recv[tau][e + 1] : pka[tau][u + 1];
            pf.wd[2] = hi ? pka[tau][u + 2]  : recv[tau][e];
            pf.wd[3] = hi ? pka[tau][u + 3]  : recv[tau][e + 1];
#pragma unroll
            for (int dt = 0; dt < 2; dt++)
                oacc[dt] = __builtin_amdgcn_mfma_f32_32x32x16_f16(vf[dt][kp], pf.v, oacc[dt], 0, 0, 0);
        }
        *(u16x8*)&Vs[nxt][vw0] = nv0;
        *(u16x8*)&Vs[nxt][vw1] = nv1;
    };

    for (int kt2 = 0; kt2 < 32; kt2 += 2) {
        tile(kt2,     std::integral_constant<int, 0>{});
        tile(kt2 + 1, std::integral_constant<int, 1>{});
    }

    float tot = rl + __shfl_xor(rl, 32, 64);
    float inv = 1.0f / tot;
    long t = qt0 + la;
    unsigned short* aor = ao + (long)(b * T_ + t) * D_ + h * 64 + (hi ? 4 : 0);
#pragma unroll
    for (int dt = 0; dt < 2; dt++)
#pragma unroll
        for (int r4 = 0; r4 < 4; r4++) {
            unsigned long long pk;
            pk  = (unsigned long long)f2h(oacc[dt][4 * r4 + 0] * inv);
            pk |= (unsigned long long)f2h(oacc[dt][4 * r4 + 1] * inv) << 16;
            pk |= (unsigned long long)f2h(oacc[dt][4 * r4 + 2] * inv) << 32;
            pk |= (unsigned long long)f2h(oacc[dt][4 * r4 + 3] * inv) << 48;
            *(unsigned long long*)&aor[dt * 32 + 8 * r4] = pk;
        }
}

// ---------------------------------------------------------------- launch
extern "C" void kernel_launch(void* const* d_in, const int* in_sizes, int n_in,
                              void* d_out, int out_size, void* d_ws, size_t ws_size,
                              hipStream_t stream) {
    const float* x    = (const float*)d_in[0];
    const float* cosb = (const float*)d_in[1];
    const float* sinb = (const float*)d_in[2];
    const float* Wq   = (const float*)d_in[3];
    const float* Wkv  = (const float*)d_in[4];
    const float* Wo   = (const float*)d_in[5];
    float* out = (float*)d_out;

    char* ws = (char*)d_ws;
    unsigned short* xb   = (unsigned short*)(ws);              // reused as attnout
    unsigned short* wcat = (unsigned short*)(ws + 16777216);   // [Wq ; Wkv]
    unsigned short* wob  = (unsigned short*)(ws + 19922944);
    unsigned short* qsb  = (unsigned short*)(ws + 47185920);
    unsigned short* vtb  = (unsigned short*)(ws + 63963136);
    unsigned short* kbuf = (unsigned short*)(ws + 68157440);

    k_cast<<<2048, 256, 0, stream>>>(x,   xb,             (B_ * T_ * D_) / 4);
    k_cast<<<1024, 256, 0, stream>>>(Wq,  wcat,           (D_ * D_) / 4);
    k_cast<<<512,  256, 0, stream>>>(Wkv, wcat + D_ * D_, (512 * D_) / 4);
    k_cast<<<1024, 256, 0, stream>>>(Wo,  wob,            (D_ * D_) / 4);

    // QKV GEMM with fused RoPE + Q/K/V^T scatter (k_rope + qkv buffer eliminated)
    k_gemm_bt<2><<<dim3(NQKV_ / 128, (B_ * T_) / 128), 256, 0, stream>>>(
        xb, wcat, nullptr, B_ * T_, NQKV_, D_, cosb, sinb, qsb, kbuf, vtb);
    k_attn<<<dim3(T_ / 128, B_ * HQ_), 256, 0, stream>>>(qsb, kbuf, vtb, xb);
    k_gemm_bt<0><<<dim3(D_ / 128, (B_ * T_) / 128), 256, 0, stream>>>(xb, wob, out, B_ * T_, D_, D_);
}